// Round 13
// baseline (548.079 us; speedup 1.0000x reference)
//
#include <hip/hip_runtime.h>

#define SEQ   2048
#define BATCH 32
#define INF   256
#define NST   512
#define OUTF  256
#define CLEN  32
#define NCH   64
#define NJOB  4
#define NCG   (NCH / NJOB)          /* 16 groups of 128 timesteps */
#define NFBLK 256                   /* fused grid: one block per CU */

typedef __bf16 bf16;
typedef __bf16 bf16x8 __attribute__((ext_vector_type(8)));
typedef float  f32x4  __attribute__((ext_vector_type(4)));
typedef unsigned long long ull;

// ---------------------------------------------------------------------------
// K1: lam=exp(-exp(ll)); lamG=lam^128; B'=gamma*B (bf16); C (bf16)
// ---------------------------------------------------------------------------
__global__ void k_prep(const float* __restrict__ ll,
                       const float* __restrict__ Bm,
                       const float* __restrict__ Cm,
                       float* __restrict__ lam,
                       float* __restrict__ lamG,
                       bf16* __restrict__ Bb,
                       bf16* __restrict__ Cb) {
  int i = blockIdx.x * 256 + threadIdx.x;
  if (i < NST) {
    float e = expf(ll[i]);
    float lmb = expf(-e);
    lam[i] = lmb;
    float p = lmb;
#pragma unroll
    for (int q = 0; q < 7; ++q) p *= p;    // lambda^128
    lamG[i] = p;
  }
  if (i < NST * INF) {
    int n = i >> 8;
    float lmb = expf(-expf(ll[n]));
    float g = sqrtf(1.0f - lmb * lmb + 1e-7f);
    Bb[i] = (bf16)(Bm[i] * g);
  }
  if (i < OUTF * NST) {
    Cb[i] = (bf16)(Cm[i]);
  }
}

// ---------------------------------------------------------------------------
// x staging helpers. xs layout: [t][i] bf16, byte = (t*512+i*2) ^ ((t&15)<<4)
// ---------------------------------------------------------------------------
__device__ __forceinline__ void xload(const float* __restrict__ xp, int tid,
                                      float4 xr[4]) {
#pragma unroll
  for (int rep = 0; rep < 4; ++rep) {
    int slot = rep * 512 + tid;
    int row = slot >> 6, col4 = slot & 63;
    xr[rep] = *(const float4*)(xp + (size_t)row * (BATCH * INF) + col4 * 4);
  }
}

__device__ __forceinline__ void xstore(char* xsb, int tid, const float4 xr[4]) {
#pragma unroll
  for (int rep = 0; rep < 4; ++rep) {
    int slot = rep * 512 + tid;
    int row = slot >> 6, col4 = slot & 63;
    union { bf16 h[4]; ull u; } pk;
    pk.h[0] = (bf16)xr[rep].x; pk.h[1] = (bf16)xr[rep].y;
    pk.h[2] = (bf16)xr[rep].z; pk.h[3] = (bf16)xr[rep].w;
    int byte = (row * (INF * 2) + col4 * 8) ^ ((row & 15) << 4);
    *(ull*)(xsb + byte) = pk.u;
  }
}

// ---------------------------------------------------------------------------
// in-register segmented scan over one chunk (32 t). acc b->s in place.
// lane holds t = mt*16 + kg*4 + r at n = n0 + nt*16 + rl. carry in/out f32.
// ---------------------------------------------------------------------------
__device__ __forceinline__ void reg_scan(f32x4 acc[2][4], float carry[4],
                                         const float la[4], const float l4[4],
                                         int kg, int rl) {
#pragma unroll
  for (int mt = 0; mt < 2; ++mt) {
    float sl[4][4];
#pragma unroll
    for (int nt = 0; nt < 4; ++nt) {
      sl[nt][0] = acc[mt][nt][0];
      sl[nt][1] = fmaf(la[nt], sl[nt][0], acc[mt][nt][1]);
      sl[nt][2] = fmaf(la[nt], sl[nt][1], acc[mt][nt][2]);
      sl[nt][3] = fmaf(la[nt], sl[nt][2], acc[mt][nt][3]);
    }
    float G[4];
#pragma unroll
    for (int nt = 0; nt < 4; ++nt) {
      float g1 = __shfl_up(sl[nt][3], 16);
      G[nt] = (kg >= 1) ? fmaf(l4[nt], g1, sl[nt][3]) : sl[nt][3];
    }
#pragma unroll
    for (int nt = 0; nt < 4; ++nt) {
      float l8 = l4[nt] * l4[nt];
      float g2 = __shfl_up(G[nt], 32);
      G[nt] = (kg >= 2) ? fmaf(l8, g2, G[nt]) : G[nt];
    }
#pragma unroll
    for (int nt = 0; nt < 4; ++nt) {
      float X = __shfl_up(G[nt], 16);
      X = (kg >= 1) ? X : 0.0f;
      float l8 = l4[nt] * l4[nt];
      float p4k = ((kg & 1) ? l4[nt] : 1.0f) * ((kg & 2) ? l8 : 1.0f);
      float cin = fmaf(p4k, carry[nt], X);
      float l2 = la[nt] * la[nt], l3 = l2 * la[nt];
      acc[mt][nt][0] = fmaf(la[nt], cin, sl[nt][0]);
      acc[mt][nt][1] = fmaf(l2, cin, sl[nt][1]);
      acc[mt][nt][2] = fmaf(l3, cin, sl[nt][2]);
      acc[mt][nt][3] = fmaf(l4[nt], cin, sl[nt][3]);
    }
#pragma unroll
    for (int nt = 0; nt < 4; ++nt)
      carry[nt] = __shfl(acc[mt][nt][3], rl + 48);
  }
}

// ---------------------------------------------------------------------------
// Manual grid barrier (sense via generation counter). All NFBLK blocks must be
// resident (grid == CU count, 1 block/CU by LDS). Device-scope fences ensure
// Z visibility across XCDs.
// ---------------------------------------------------------------------------
__device__ __forceinline__ void grid_barrier(unsigned* cnt, unsigned* gen) {
  __threadfence();           // release this thread's prior global writes
  __syncthreads();
  if (threadIdx.x == 0) {
    unsigned g = __hip_atomic_load(gen, __ATOMIC_ACQUIRE, __HIP_MEMORY_SCOPE_AGENT);
    unsigned arrived = __hip_atomic_fetch_add(cnt, 1u, __ATOMIC_ACQ_REL,
                                              __HIP_MEMORY_SCOPE_AGENT) + 1u;
    if (arrived == (unsigned)NFBLK) {
      __hip_atomic_store(cnt, 0u, __ATOMIC_RELEASE, __HIP_MEMORY_SCOPE_AGENT);
      __hip_atomic_fetch_add(gen, 1u, __ATOMIC_ACQ_REL, __HIP_MEMORY_SCOPE_AGENT);
    } else {
      while (__hip_atomic_load(gen, __ATOMIC_ACQUIRE, __HIP_MEMORY_SCOPE_AGENT) == g) {}
    }
  }
  __syncthreads();
  __threadfence();           // acquire side
}

// ---------------------------------------------------------------------------
// FUSED: block = (cg, bA); two pairs (bA, bA+16) sequentially.
// scan -> states in LDS -> Z -> grid barrier -> own S0 from Z -> in-LDS fixup
// -> GEMM2 from LDS -> out. No b_seq/state buffer ever touches HBM.
// ---------------------------------------------------------------------------
__global__ __launch_bounds__(512, 2)
void k_fused(const float* __restrict__ x, const bf16* __restrict__ Bb,
             const bf16* __restrict__ Cb, const float* __restrict__ lam,
             const float* __restrict__ lamG, float* __restrict__ Z,
             float* __restrict__ out, float* __restrict__ fin,
             unsigned* __restrict__ barcnt, unsigned* __restrict__ bargen) {
  __shared__ __align__(16) char ssm[128 * NST * 2];   // 128KB local states
  __shared__ __align__(16) char xs[CLEN * INF * 2];   // 16KB x chunk
  __shared__ float s0sh[NST];                          // 2KB group-carry

  const int tid = threadIdx.x, wid = tid >> 6, lane = tid & 63;
  const int rl = lane & 15, kg = lane >> 4;
  const int cg = blockIdx.x >> 4, bA = blockIdx.x & 15;
  const int n0 = wid * 64;

  float la[4], l4[4];
#pragma unroll
  for (int nt = 0; nt < 4; ++nt) {
    float v = lam[n0 + nt * 16 + rl];
    la[nt] = v; l4[nt] = (v * v) * (v * v);
  }

#pragma unroll 1
  for (int pp = 0; pp < 2; ++pp) {
    const int b = bA + pp * 16;

    // ---- B' panel into registers (per pair, keeps GEMM2 regs free)
    bf16x8 Breg[8][4];
#pragma unroll
    for (int k = 0; k < 8; ++k)
#pragma unroll
      for (int nt = 0; nt < 4; ++nt)
        Breg[k][nt] = *(const bf16x8*)(Bb + (size_t)(n0 + nt * 16 + rl) * INF + k * 32 + kg * 8);

    // ---- scan phase: 4 jobs, states -> ssm
    float carry[4] = {0.f, 0.f, 0.f, 0.f};
#pragma unroll 1
    for (int jj = 0; jj < NJOB; ++jj) {
      const int c = cg * NJOB + jj;
      float4 xr[4];
      xload(x + ((size_t)(c * CLEN) * BATCH + b) * INF, tid, xr);
      __syncthreads();                   // xs free (prev GEMM1 / prev pair done)
      xstore(xs, tid, xr);
      __syncthreads();                   // xs ready

      f32x4 acc[2][4] = {};
#pragma unroll
      for (int k = 0; k < 8; ++k) {
        bf16x8 af[2];
#pragma unroll
        for (int mt = 0; mt < 2; ++mt) {
          int row = mt * 16 + rl;
          int byte = (row * (INF * 2) + (k * 32 + kg * 8) * 2) ^ (rl << 4);
          af[mt] = *(const bf16x8*)(&xs[0] + byte);
        }
#pragma unroll
        for (int mt = 0; mt < 2; ++mt)
#pragma unroll
          for (int nt = 0; nt < 4; ++nt)
            acc[mt][nt] = __builtin_amdgcn_mfma_f32_16x16x32_bf16(af[mt], Breg[k][nt], acc[mt][nt], 0, 0, 0);
      }

      reg_scan(acc, carry, la, l4, kg, rl);

      // local states -> ssm (bf16, swizzled): row dt = jj*32 + t
#pragma unroll
      for (int mt = 0; mt < 2; ++mt)
#pragma unroll
        for (int nt = 0; nt < 4; ++nt)
#pragma unroll
          for (int r = 0; r < 4; ++r) {
            int t = jj * 32 + mt * 16 + kg * 4 + r;
            int n = n0 + nt * 16 + rl;
            int byte = (t * (NST * 2) + n * 2) ^ ((t & 15) << 4);
            *(bf16*)(&ssm[0] + byte) = (bf16)acc[mt][nt][r];
          }
    }

    // group-final state -> Z
    if (kg == 0)
#pragma unroll
      for (int nt = 0; nt < 4; ++nt)
        Z[((size_t)cg * BATCH + b) * NST + n0 + nt * 16 + rl] = carry[nt];

    // ---- all groups' Z visible everywhere
    grid_barrier(barcnt, bargen);

    // ---- own S0 (thread owns n = tid); fin from last group
    {
      float lG = lamG[tid];
      float s0 = 0.f;
      for (int g = 0; g < cg; ++g)
        s0 = fmaf(lG, s0, Z[((size_t)g * BATCH + b) * NST + tid]);
      s0sh[tid] = s0;
      if (cg == NCG - 1)
        fin[(size_t)b * NST + tid] =
            fmaf(lG, s0, Z[((size_t)(NCG - 1) * BATCH + b) * NST + tid]);
    }
    __syncthreads();

    // ---- in-LDS carry fixup: s[dt][n] += lambda_n^(dt+1) * S0[n]
    {
      const int n = tid;
      float lm = lam[n], e = lm, s0 = s0sh[n];
#pragma unroll 8
      for (int dt = 0; dt < 128; ++dt) {
        int byte = (dt * (NST * 2) + n * 2) ^ ((dt & 15) << 4);
        bf16* p = (bf16*)(&ssm[0] + byte);
        *p = (bf16)fmaf(e, s0, (float)*p);
        e *= lm;
      }
    }
    __syncthreads();

    // ---- GEMM2: wave = 64 rows x 64 o; A from ssm, C from L2 (prefetched)
    {
      const int wr = wid >> 2, wc = wid & 3;
      const int r0 = wr * 64, o0 = wc * 64;
      f32x4 a2[4][4] = {};
      bf16x8 cf[4], cfn[4];
#pragma unroll
      for (int of = 0; of < 4; ++of)
        cf[of] = *(const bf16x8*)(Cb + (size_t)(o0 + of * 16 + rl) * NST + kg * 8);
#pragma unroll
      for (int kq = 0; kq < 16; ++kq) {
        const int k0 = kq * 32;
        if (kq < 15)
#pragma unroll
          for (int of = 0; of < 4; ++of)
            cfn[of] = *(const bf16x8*)(Cb + (size_t)(o0 + of * 16 + rl) * NST + k0 + 32 + kg * 8);
#pragma unroll
        for (int mf = 0; mf < 4; ++mf) {
          int t = r0 + mf * 16 + rl;
          bf16x8 af = *(const bf16x8*)(&ssm[0] +
              ((t * (NST * 2) + (k0 + kg * 8) * 2) ^ ((t & 15) << 4)));
#pragma unroll
          for (int of = 0; of < 4; ++of)
            a2[mf][of] = __builtin_amdgcn_mfma_f32_16x16x32_bf16(af, cf[of], a2[mf][of], 0, 0, 0);
        }
        if (kq < 15) {
#pragma unroll
          for (int of = 0; of < 4; ++of) cf[of] = cfn[of];
        }
      }
      // epilogue: D row=(lane>>4)*4+reg, col=lane&15
#pragma unroll
      for (int mf = 0; mf < 4; ++mf)
#pragma unroll
        for (int of = 0; of < 4; ++of)
#pragma unroll
          for (int r = 0; r < 4; ++r) {
            size_t srow = (size_t)cg * 128 + r0 + mf * 16 + kg * 4 + r;
            int o = o0 + of * 16 + rl;
            out[(srow * BATCH + b) * OUTF + o] = a2[mf][of][r];
          }
    }
  }
}

// ---------------------------------------------------------------------------
extern "C" void kernel_launch(void* const* d_in, const int* in_sizes, int n_in,
                              void* d_out, int out_size, void* d_ws, size_t ws_size,
                              hipStream_t stream) {
  const float* x  = (const float*)d_in[0];
  const float* ll = (const float*)d_in[1];
  const float* Bm = (const float*)d_in[2];
  const float* Cm = (const float*)d_in[3];

  char* ws = (char*)d_ws;
  float* lam  = (float*)(ws);
  float* lamG = (float*)(ws + 2048);
  bf16*  Bb   = (bf16*)(ws + 4096);
  bf16*  Cb   = (bf16*)(ws + 4096 + NST * INF * 2);
  float* Z    = (float*)(ws + 4096 + NST * INF * 2 + OUTF * NST * 2);
  unsigned* bar = (unsigned*)((char*)Z + (size_t)NCG * BATCH * NST * 4);
  // total ws use: ~1.6 MB

  float* out = (float*)d_out;
  float* fin = out + (size_t)SEQ * BATCH * OUTF;

  hipMemsetAsync(bar, 0, 8, stream);   // barrier counters must start at 0
  k_prep<<<dim3(512), dim3(256), 0, stream>>>(ll, Bm, Cm, lam, lamG, Bb, Cb);
  k_fused<<<dim3(NFBLK), dim3(512), 0, stream>>>(x, Bb, Cb, lam, lamG, Z,
                                                 out, fin, bar, bar + 1);
}

// Round 14
// 121.215 us; speedup vs baseline: 4.5216x; 4.5216x over previous
//
#include <hip/hip_runtime.h>

#define SEQ   2048
#define BATCH 32
#define INF   256
#define NST   512
#define OUTF  256
#define CLEN  32
#define NCH   64
#define NJOB  4
#define NCG   (NCH / NJOB)          /* 16 chunk-groups of 128 timesteps */
#define NBLK  (NCG * BATCH)         /* 512 blocks */

typedef __bf16 bf16;
typedef __bf16 bf16x8 __attribute__((ext_vector_type(8)));
typedef float  f32x4  __attribute__((ext_vector_type(4)));
typedef unsigned long long ull;

// ---------------------------------------------------------------------------
// K1: lam=exp(-exp(ll)); lamG=lam^128; l2la=log2(lam); B'=gamma*B bf16; C bf16
// ---------------------------------------------------------------------------
__global__ void k_prep(const float* __restrict__ ll,
                       const float* __restrict__ Bm,
                       const float* __restrict__ Cm,
                       float* __restrict__ lam,
                       float* __restrict__ lamG,
                       float* __restrict__ l2la,
                       bf16* __restrict__ Bb,
                       bf16* __restrict__ Cb) {
  int i = blockIdx.x * 256 + threadIdx.x;
  if (i < NST) {
    float e = expf(ll[i]);          // -ln(lambda)
    float lmb = expf(-e);
    lam[i] = lmb;
    l2la[i] = -e * 1.44269504088896341f;   // log2(lambda)
    float p = lmb;
#pragma unroll
    for (int q = 0; q < 7; ++q) p *= p;    // lambda^128
    lamG[i] = p;
  }
  if (i < NST * INF) {
    int n = i >> 8;
    float lmb = expf(-expf(ll[n]));
    float g = sqrtf(1.0f - lmb * lmb + 1e-7f);
    Bb[i] = (bf16)(Bm[i] * g);
  }
  if (i < OUTF * NST) {
    Cb[i] = (bf16)(Cm[i]);
  }
}

// ---------------------------------------------------------------------------
// x staging helpers. xs layout: [t][i] bf16, byte = (t*512+i*2) ^ ((t&15)<<4)
// ---------------------------------------------------------------------------
__device__ __forceinline__ void xload(const float* __restrict__ xp, int tid,
                                      float4 xr[4]) {
#pragma unroll
  for (int rep = 0; rep < 4; ++rep) {
    int slot = rep * 512 + tid;
    int row = slot >> 6, col4 = slot & 63;
    xr[rep] = *(const float4*)(xp + (size_t)row * (BATCH * INF) + col4 * 4);
  }
}

__device__ __forceinline__ void xstore(char* xsb, int tid, const float4 xr[4]) {
#pragma unroll
  for (int rep = 0; rep < 4; ++rep) {
    int slot = rep * 512 + tid;
    int row = slot >> 6, col4 = slot & 63;
    union { bf16 h[4]; ull u; } pk;
    pk.h[0] = (bf16)xr[rep].x; pk.h[1] = (bf16)xr[rep].y;
    pk.h[2] = (bf16)xr[rep].z; pk.h[3] = (bf16)xr[rep].w;
    int byte = (row * (INF * 2) + col4 * 8) ^ ((row & 15) << 4);
    *(ull*)(xsb + byte) = pk.u;
  }
}

// ---------------------------------------------------------------------------
// in-register segmented scan over one chunk (32 t). acc b->s in place.
// ---------------------------------------------------------------------------
__device__ __forceinline__ void reg_scan(f32x4 acc[2][4], float carry[4],
                                         const float la[4], const float l4[4],
                                         int kg, int rl) {
#pragma unroll
  for (int mt = 0; mt < 2; ++mt) {
    float sl[4][4];
#pragma unroll
    for (int nt = 0; nt < 4; ++nt) {
      sl[nt][0] = acc[mt][nt][0];
      sl[nt][1] = fmaf(la[nt], sl[nt][0], acc[mt][nt][1]);
      sl[nt][2] = fmaf(la[nt], sl[nt][1], acc[mt][nt][2]);
      sl[nt][3] = fmaf(la[nt], sl[nt][2], acc[mt][nt][3]);
    }
    float G[4];
#pragma unroll
    for (int nt = 0; nt < 4; ++nt) {
      float g1 = __shfl_up(sl[nt][3], 16);
      G[nt] = (kg >= 1) ? fmaf(l4[nt], g1, sl[nt][3]) : sl[nt][3];
    }
#pragma unroll
    for (int nt = 0; nt < 4; ++nt) {
      float l8 = l4[nt] * l4[nt];
      float g2 = __shfl_up(G[nt], 32);
      G[nt] = (kg >= 2) ? fmaf(l8, g2, G[nt]) : G[nt];
    }
#pragma unroll
    for (int nt = 0; nt < 4; ++nt) {
      float X = __shfl_up(G[nt], 16);
      X = (kg >= 1) ? X : 0.0f;
      float l8 = l4[nt] * l4[nt];
      float p4k = ((kg & 1) ? l4[nt] : 1.0f) * ((kg & 2) ? l8 : 1.0f);
      float cin = fmaf(p4k, carry[nt], X);
      float l2 = la[nt] * la[nt], l3 = l2 * la[nt];
      acc[mt][nt][0] = fmaf(la[nt], cin, sl[nt][0]);
      acc[mt][nt][1] = fmaf(l2, cin, sl[nt][1]);
      acc[mt][nt][2] = fmaf(l3, cin, sl[nt][2]);
      acc[mt][nt][3] = fmaf(l4[nt], cin, sl[nt][3]);
    }
#pragma unroll
    for (int nt = 0; nt < 4; ++nt)
      carry[nt] = __shfl(acc[mt][nt][3], rl + 48);
  }
}

// ---------------------------------------------------------------------------
// GEMM1 with B' streamed from L2 (fallback path only)
// ---------------------------------------------------------------------------
__device__ __forceinline__ void gemm1_l2(const char* xsb, const bf16* __restrict__ Bb,
                                         f32x4 acc[2][4], int n0, int rl, int kg) {
#pragma unroll
  for (int k = 0; k < 8; ++k) {
    bf16x8 af[2], bfr[4];
#pragma unroll
    for (int mt = 0; mt < 2; ++mt) {
      int row = mt * 16 + rl;
      int byte = (row * (INF * 2) + (k * 32 + kg * 8) * 2) ^ (rl << 4);
      af[mt] = *(const bf16x8*)(xsb + byte);
    }
#pragma unroll
    for (int nt = 0; nt < 4; ++nt)
      bfr[nt] = *(const bf16x8*)(Bb + (size_t)(n0 + nt * 16 + rl) * INF + k * 32 + kg * 8);
#pragma unroll
    for (int mt = 0; mt < 2; ++mt)
#pragma unroll
      for (int nt = 0; nt < 4; ++nt)
        acc[mt][nt] = __builtin_amdgcn_mfma_f32_16x16x32_bf16(af[mt], bfr[nt], acc[mt][nt], 0, 0, 0);
  }
}

// ---------------------------------------------------------------------------
// PASS0F v2: 4 single-use xs buffers (64KB); only 2 barriers in the job loop;
// bfrag stores AFTER the barrier (store-ack drain hidden under next job).
// bfrag index (8B units): ((((cg*32+b)*4+jj)*8+wid)*8 + mt*4+nt)*64 + lane
// ---------------------------------------------------------------------------
__global__ __launch_bounds__(512, 2)
void k_pass0f(const float* __restrict__ x, const bf16* __restrict__ Bb,
              const float* __restrict__ lam, float* __restrict__ Z,
              ull* __restrict__ bfrag) {
  __shared__ __align__(16) char xs[4][CLEN * INF * 2];   // 4x16KB

  const int tid = threadIdx.x, wid = tid >> 6, lane = tid & 63;
  const int rl = lane & 15, kg = lane >> 4;
  const int b = blockIdx.x >> 4, cg = blockIdx.x & 15;
  const int n0 = wid * 64;

  float la[4], l4[4], carry[4];
#pragma unroll
  for (int nt = 0; nt < 4; ++nt) {
    float v = lam[n0 + nt * 16 + rl];
    la[nt] = v; l4[nt] = (v * v) * (v * v);
    carry[nt] = 0.0f;
  }

  bf16x8 Breg[8][4];
#pragma unroll
  for (int k = 0; k < 8; ++k)
#pragma unroll
    for (int nt = 0; nt < 4; ++nt)
      Breg[k][nt] = *(const bf16x8*)(Bb + (size_t)(n0 + nt * 16 + rl) * INF + k * 32 + kg * 8);

  // prologue: stage jobs 0 and 1
  {
    float4 xr[4];
    xload(x + ((size_t)(cg * NJOB * CLEN) * BATCH + b) * INF, tid, xr);
    xstore(xs[0], tid, xr);
    xload(x + ((size_t)((cg * NJOB + 1) * CLEN) * BATCH + b) * INF, tid, xr);
    xstore(xs[1], tid, xr);
  }
  __syncthreads();

#pragma unroll
  for (int jj = 0; jj < NJOB; ++jj) {
    const int c = cg * NJOB + jj;
    f32x4 acc[2][4] = {};
#pragma unroll
    for (int k = 0; k < 8; ++k) {
      bf16x8 af[2];
#pragma unroll
      for (int mt = 0; mt < 2; ++mt) {
        int row = mt * 16 + rl;
        int byte = (row * (INF * 2) + (k * 32 + kg * 8) * 2) ^ (rl << 4);
        af[mt] = *(const bf16x8*)(&xs[jj][0] + byte);
      }
#pragma unroll
      for (int mt = 0; mt < 2; ++mt)
#pragma unroll
        for (int nt = 0; nt < 4; ++nt)
          acc[mt][nt] = __builtin_amdgcn_mfma_f32_16x16x32_bf16(af[mt], Breg[k][nt], acc[mt][nt], 0, 0, 0);
    }

    float4 xr[4];
    if (jj < 2)
      xload(x + ((size_t)((c + 2) * CLEN) * BATCH + b) * INF, tid, xr);

    reg_scan(acc, carry, la, l4, kg, rl);

    if (jj < 2) {
      xstore(xs[jj + 2], tid, xr);
      __syncthreads();           // xs[jj+2] visible for iteration jj+2
    }

    // fragment-native stores AFTER the barrier: drain overlaps next job
    {
      ull* dst = bfrag + ((size_t)(((cg * BATCH + b) * NJOB + jj) * 8 + wid)) * 512 + lane;
#pragma unroll
      for (int mt = 0; mt < 2; ++mt)
#pragma unroll
        for (int nt = 0; nt < 4; ++nt) {
          union { bf16 h[4]; ull u; } pk;
          pk.h[0] = (bf16)acc[mt][nt][0];
          pk.h[1] = (bf16)acc[mt][nt][1];
          pk.h[2] = (bf16)acc[mt][nt][2];
          pk.h[3] = (bf16)acc[mt][nt][3];
          dst[(mt * 4 + nt) * 64] = pk.u;
        }
    }

    if (jj == NJOB - 1) {
      if (kg == 0)
#pragma unroll
        for (int nt = 0; nt < 4; ++nt)
          Z[((size_t)cg * BATCH + b) * NST + n0 + nt * 16 + rl] = carry[nt];
    }
  }
}

// ---------------------------------------------------------------------------
// K3: exclusive prefix over groups: S0[g] = lamG*S0[g-1] + Z[g-1]; writes fin.
// ---------------------------------------------------------------------------
__global__ __launch_bounds__(128)
void k_chain(const float* __restrict__ Z, const float* __restrict__ lamG,
             float* __restrict__ S0, float* __restrict__ fin) {
  const int b = blockIdx.x;
  const int n = blockIdx.y * 128 + threadIdx.x;
  const float lG = lamG[n];
  float z[NCG];
#pragma unroll
  for (int g = 0; g < NCG; ++g)
    z[g] = Z[((size_t)g * BATCH + b) * NST + n];
  float s = 0.0f;
#pragma unroll
  for (int g = 0; g < NCG; ++g) {
    S0[((size_t)g * BATCH + b) * NST + n] = s;
    s = fmaf(lG, s, z[g]);
  }
  fin[(size_t)b * NST + n] = s;
}

// ---------------------------------------------------------------------------
// GEMM2D: per block = (c 0..63, b): ONE pass0f job = 32 t-rows x 256 o.
// 32KB ss -> 4 blocks/CU. Stage fragment-layout panel with fused fixup,
// then K-loop with C software-prefetch.
// ---------------------------------------------------------------------------
__global__ __launch_bounds__(512)
void k_gemm2d(const ull* __restrict__ bfrag, const bf16* __restrict__ Cb,
              const float* __restrict__ S0, const float* __restrict__ l2la,
              float* __restrict__ out) {
  __shared__ __align__(16) char ss[32 * NST * 2];   // 32 rows x 1KB, XOR swz

  const int tid = threadIdx.x, wid = tid >> 6, lane = tid & 63;
  const int rl = lane & 15, kg = lane >> 4;
  const int c = blockIdx.x >> 5, b = blockIdx.x & 31;
  const int cg = c >> 2, jj = c & 3;

  // ---- stage: one job = 4096 8B chunks, 8 per thread
  const ull* src8 = bfrag + ((size_t)((cg * BATCH + b) * NJOB + jj)) * 4096;
  const float* S0g = S0 + ((size_t)cg * BATCH + b) * NST;
#pragma unroll
  for (int q = 0; q < 8; ++q) {
    int chunk = q * 512 + tid;
    int widx = chunk >> 9;
    int fr = (chunk >> 6) & 7;
    int mt = fr >> 2, nt = fr & 3;
    int ls = chunk & 63;
    int kgs = ls >> 4, rls = ls & 15;
    int n = widx * 64 + nt * 16 + rls;
    int t0 = mt * 16 + kgs * 4;                    // row within 32-tile
    int dt0 = jj * 32 + t0;                        // row within 128-group

    union { ull u; bf16 h[4]; } in;
    in.u = src8[chunk];
    float l2 = l2la[n];
    float s0 = S0g[n];
    float e = exp2f((float)(dt0 + 1) * l2);        // lambda^(dt0+1)
    float lm = exp2f(l2);                          // lambda
#pragma unroll
    for (int r = 0; r < 4; ++r) {
      float s = fmaf(e, s0, (float)in.h[r]);
      int t = t0 + r;
      int byte = (t * (NST * 2) + n * 2) ^ ((t & 15) << 4);
      *(bf16*)(&ss[0] + byte) = (bf16)s;
      e *= lm;
    }
  }
  __syncthreads();

  // ---- K-loop: wave owns o-panel [wid*32, +32), all 32 rows; C prefetched
  const int o0 = wid * 32;
  f32x4 acc[2][2] = {};
  bf16x8 cf[2];
#pragma unroll
  for (int ot2 = 0; ot2 < 2; ++ot2)
    cf[ot2] = *(const bf16x8*)(Cb + (size_t)(o0 + ot2 * 16 + rl) * NST + kg * 8);
#pragma unroll
  for (int kq = 0; kq < 16; ++kq) {
    const int k0 = kq * 32;
    bf16x8 cfn[2];
    if (kq < 15)
#pragma unroll
      for (int ot2 = 0; ot2 < 2; ++ot2)
        cfn[ot2] = *(const bf16x8*)(Cb + (size_t)(o0 + ot2 * 16 + rl) * NST + k0 + 32 + kg * 8);
    bf16x8 af[2];
#pragma unroll
    for (int mf = 0; mf < 2; ++mf) {
      int t = mf * 16 + rl;
      af[mf] = *(const bf16x8*)(&ss[0] +
          ((t * (NST * 2) + (k0 + kg * 8) * 2) ^ ((t & 15) << 4)));
    }
#pragma unroll
    for (int mf = 0; mf < 2; ++mf)
#pragma unroll
      for (int ot2 = 0; ot2 < 2; ++ot2)
        acc[mf][ot2] = __builtin_amdgcn_mfma_f32_16x16x32_bf16(af[mf], cf[ot2], acc[mf][ot2], 0, 0, 0);
    if (kq < 15) {
      cf[0] = cfn[0]; cf[1] = cfn[1];
    }
  }

  // ---- epilogue: D row=(lane>>4)*4+reg, col=lane&15
#pragma unroll
  for (int mf = 0; mf < 2; ++mf)
#pragma unroll
    for (int ot2 = 0; ot2 < 2; ++ot2)
#pragma unroll
      for (int r = 0; r < 4; ++r) {
        int ml = mf * 16 + kg * 4 + r;
        size_t srow = (size_t)c * 32 + ml;
        int o = o0 + ot2 * 16 + rl;
        out[(srow * BATCH + b) * OUTF + o] = acc[mf][ot2][r];
      }
}

// ---------------------------------------------------------------------------
// Fallback: pass0 (old orientation, Z only) + fused pass1 (R5-proven ~142us)
// ---------------------------------------------------------------------------
__global__ __launch_bounds__(512, 2)
void k_pass0_fb(const float* __restrict__ x, const bf16* __restrict__ Bb,
                const float* __restrict__ lam, float* __restrict__ Z) {
  __shared__ __align__(16) char xs[2][CLEN * INF * 2];

  const int tid = threadIdx.x, wid = tid >> 6, lane = tid & 63;
  const int rl = lane & 15, kg = lane >> 4;
  const int b = blockIdx.x >> 4, cg = blockIdx.x & 15;
  const int n0 = wid * 64;

  float la[4], l4[4], carry[4];
#pragma unroll
  for (int nt = 0; nt < 4; ++nt) {
    float v = lam[n0 + nt * 16 + rl];
    la[nt] = v; l4[nt] = (v * v) * (v * v);
    carry[nt] = 0.0f;
  }

  bf16x8 Breg[8][4];
#pragma unroll
  for (int k = 0; k < 8; ++k)
#pragma unroll
    for (int nt = 0; nt < 4; ++nt)
      Breg[k][nt] = *(const bf16x8*)(Bb + (size_t)(n0 + nt * 16 + rl) * INF + k * 32 + kg * 8);

  {
    float4 xr0[4];
    xload(x + ((size_t)(cg * NJOB * CLEN) * BATCH + b) * INF, tid, xr0);
    xstore(xs[0], tid, xr0);
  }
  __syncthreads();

#pragma unroll
  for (int jj = 0; jj < NJOB; ++jj) {
    const int c = cg * NJOB + jj;
    f32x4 acc[2][4] = {};
#pragma unroll
    for (int k = 0; k < 8; ++k) {
      bf16x8 af[2];
#pragma unroll
      for (int mt = 0; mt < 2; ++mt) {
        int row = mt * 16 + rl;
        int byte = (row * (INF * 2) + (k * 32 + kg * 8) * 2) ^ (rl << 4);
        af[mt] = *(const bf16x8*)(&xs[jj & 1][0] + byte);
      }
#pragma unroll
      for (int mt = 0; mt < 2; ++mt)
#pragma unroll
        for (int nt = 0; nt < 4; ++nt)
          acc[mt][nt] = __builtin_amdgcn_mfma_f32_16x16x32_bf16(af[mt], Breg[k][nt], acc[mt][nt], 0, 0, 0);
    }

    if (jj < NJOB - 1) {
      float4 xr[4];
      xload(x + ((size_t)((c + 1) * CLEN) * BATCH + b) * INF, tid, xr);
      reg_scan(acc, carry, la, l4, kg, rl);
      xstore(xs[(jj + 1) & 1], tid, xr);
      __syncthreads();
    } else {
      reg_scan(acc, carry, la, l4, kg, rl);
      if (kg == 0)
#pragma unroll
        for (int nt = 0; nt < 4; ++nt)
          Z[((size_t)cg * BATCH + b) * NST + n0 + nt * 16 + rl] = carry[nt];
    }
  }
}

__global__ __launch_bounds__(512)
void k_pass1_fb(const float* __restrict__ x, const bf16* __restrict__ Bb,
                const bf16* __restrict__ Cb, const float* __restrict__ lam,
                const float* __restrict__ S0, float* __restrict__ out,
                float* __restrict__ fin) {
  __shared__ __align__(16) char xs[2][CLEN * INF * 2];
  __shared__ __align__(16) char ss[CLEN * NST * 2];

  const int tid = threadIdx.x, wid = tid >> 6, lane = tid & 63;
  const int rl = lane & 15, kg = lane >> 4;
  const int b = blockIdx.x >> 4, cg = blockIdx.x & 15;
  const int n0 = wid * 64;

  float la[4], l4[4], carry[4];
#pragma unroll
  for (int nt = 0; nt < 4; ++nt) {
    float v = lam[n0 + nt * 16 + rl];
    la[nt] = v; l4[nt] = (v * v) * (v * v);
    carry[nt] = S0[((size_t)cg * BATCH + b) * NST + n0 + nt * 16 + rl];
  }
  {
    float4 xr0[4];
    xload(x + ((size_t)(cg * NJOB * CLEN) * BATCH + b) * INF, tid, xr0);
    xstore(xs[0], tid, xr0);
  }
  __syncthreads();

#pragma unroll
  for (int jj = 0; jj < NJOB; ++jj) {
    const int c = cg * NJOB + jj;
    f32x4 acc[2][4] = {};
    gemm1_l2(&xs[jj & 1][0], Bb, acc, n0, rl, kg);
    {
      float4 xr[4];
      const int lastj = (jj == NJOB - 1);
      if (!lastj)
        xload(x + ((size_t)((c + 1) * CLEN) * BATCH + b) * INF, tid, xr);
      reg_scan(acc, carry, la, l4, kg, rl);
      if (c == NCH - 1 && kg == 0)
#pragma unroll
        for (int nt = 0; nt < 4; ++nt)
          fin[(size_t)b * NST + n0 + nt * 16 + rl] = carry[nt];
      __syncthreads();
#pragma unroll
      for (int mt = 0; mt < 2; ++mt)
#pragma unroll
        for (int nt = 0; nt < 4; ++nt)
#pragma unroll
          for (int r = 0; r < 4; ++r) {
            int t = mt * 16 + kg * 4 + r;
            int n = n0 + nt * 16 + rl;
            int byte = (t * (NST * 2) + n * 2) ^ ((t & 15) << 4);
            *(bf16*)(&ss[0] + byte) = (bf16)acc[mt][nt][r];
          }
      if (!lastj) xstore(xs[(jj + 1) & 1], tid, xr);
    }
    __syncthreads();

    const int o0 = wid * 32;
    f32x4 a2[2][2] = {};
#pragma unroll
    for (int k0 = 0; k0 < NST; k0 += 32) {
      bf16x8 af[2], cf[2];
#pragma unroll
      for (int mt = 0; mt < 2; ++mt) {
        int t = mt * 16 + rl;
        int byte = (t * (NST * 2) + (k0 + kg * 8) * 2) ^ (rl << 4);
        af[mt] = *(const bf16x8*)(&ss[0] + byte);
      }
#pragma unroll
      for (int ot = 0; ot < 2; ++ot)
        cf[ot] = *(const bf16x8*)(Cb + (size_t)(o0 + ot * 16 + rl) * NST + k0 + kg * 8);
#pragma unroll
      for (int mt = 0; mt < 2; ++mt)
#pragma unroll
        for (int ot = 0; ot < 2; ++ot)
          a2[mt][ot] = __builtin_amdgcn_mfma_f32_16x16x32_bf16(af[mt], cf[ot], a2[mt][ot], 0, 0, 0);
    }
#pragma unroll
    for (int mt = 0; mt < 2; ++mt)
#pragma unroll
      for (int ot = 0; ot < 2; ++ot)
#pragma unroll
        for (int r = 0; r < 4; ++r) {
          int t = mt * 16 + kg * 4 + r;
          int o = o0 + ot * 16 + rl;
          out[(((size_t)(c * CLEN + t)) * BATCH + b) * OUTF + o] = a2[mt][ot][r];
        }
  }
}

// ---------------------------------------------------------------------------
extern "C" void kernel_launch(void* const* d_in, const int* in_sizes, int n_in,
                              void* d_out, int out_size, void* d_ws, size_t ws_size,
                              hipStream_t stream) {
  const float* x  = (const float*)d_in[0];
  const float* ll = (const float*)d_in[1];
  const float* Bm = (const float*)d_in[2];
  const float* Cm = (const float*)d_in[3];

  char* ws = (char*)d_ws;
  float* lam  = (float*)(ws);
  float* lamG = (float*)(ws + 2048);
  float* l2la = (float*)(ws + 4096);
  bf16*  Bb   = (bf16*)(ws + 6144);
  bf16*  Cb   = (bf16*)(ws + 6144 + NST * INF * 2);
  float* Z    = (float*)(ws + 6144 + NST * INF * 2 + OUTF * NST * 2);
  float* S0   = (float*)((char*)Z + (size_t)NCG * BATCH * NST * 4);
  ull*   bfrag= (ull*)((char*)S0 + (size_t)NCG * BATCH * NST * 4);
  const size_t NEED = ((char*)bfrag - ws) + (size_t)SEQ * BATCH * NST * 2;  // ~67MB

  float* out = (float*)d_out;
  float* fin = out + (size_t)SEQ * BATCH * OUTF;

  k_prep<<<dim3(512), dim3(256), 0, stream>>>(ll, Bm, Cm, lam, lamG, l2la, Bb, Cb);
  if (ws_size >= NEED) {
    k_pass0f<<<dim3(NBLK), dim3(512), 0, stream>>>(x, Bb, lam, Z, bfrag);
    k_chain<<<dim3(BATCH, 4), dim3(128), 0, stream>>>(Z, lamG, S0, fin);
    k_gemm2d<<<dim3(2048), dim3(512), 0, stream>>>(bfrag, Cb, S0, l2la, out);
  } else {
    k_pass0_fb<<<dim3(NBLK), dim3(512), 0, stream>>>(x, Bb, lam, Z);
    k_chain<<<dim3(BATCH, 4), dim3(128), 0, stream>>>(Z, lamG, S0, fin);
    k_pass1_fb<<<dim3(NBLK), dim3(512), 0, stream>>>(x, Bb, Cb, lam, S0, out, fin);
  }
}

// Round 15
// 115.164 us; speedup vs baseline: 4.7591x; 1.0525x over previous
//
#include <hip/hip_runtime.h>

#define SEQ   2048
#define BATCH 32
#define INF   256
#define NST   512
#define OUTF  256
#define CLEN  32
#define NCH   64
#define NJOB  4
#define NCG   (NCH / NJOB)          /* 16 chunk-groups of 128 timesteps */
#define NBLK  (NCG * BATCH)         /* 512 blocks */

typedef __bf16 bf16;
typedef __bf16 bf16x8 __attribute__((ext_vector_type(8)));
typedef float  f32x4  __attribute__((ext_vector_type(4)));
typedef unsigned long long ull;

// ---------------------------------------------------------------------------
// K1: lam=exp(-exp(ll)); lamG=lam^128; Lam32[dt][n]=lam^(dt+1) (f32 table);
//     B'=gamma*B bf16; C bf16
// ---------------------------------------------------------------------------
__global__ void k_prep(const float* __restrict__ ll,
                       const float* __restrict__ Bm,
                       const float* __restrict__ Cm,
                       float* __restrict__ lam,
                       float* __restrict__ lamG,
                       float* __restrict__ Lam32,
                       bf16* __restrict__ Bb,
                       bf16* __restrict__ Cb) {
  int i = blockIdx.x * 256 + threadIdx.x;
  if (i < NST) {
    float e = expf(ll[i]);          // -ln(lambda)
    float lmb = expf(-e);
    lam[i] = lmb;
    float p = lmb;
#pragma unroll
    for (int q = 0; q < 7; ++q) p *= p;    // lambda^128
    lamG[i] = p;
    // lambda-power table: Lam32[dt*NST + i] = lambda^(dt+1)
    float ee = lmb;
    for (int dt = 0; dt < 128; ++dt) {
      Lam32[(size_t)dt * NST + i] = ee;
      ee *= lmb;
    }
  }
  if (i < NST * INF) {
    int n = i >> 8;
    float lmb = expf(-expf(ll[n]));
    float g = sqrtf(1.0f - lmb * lmb + 1e-7f);
    Bb[i] = (bf16)(Bm[i] * g);
  }
  if (i < OUTF * NST) {
    Cb[i] = (bf16)(Cm[i]);
  }
}

// ---------------------------------------------------------------------------
// x staging helpers. xs layout: [t][i] bf16, byte = (t*512+i*2) ^ ((t&15)<<4)
// ---------------------------------------------------------------------------
__device__ __forceinline__ void xload(const float* __restrict__ xp, int tid,
                                      float4 xr[4]) {
#pragma unroll
  for (int rep = 0; rep < 4; ++rep) {
    int slot = rep * 512 + tid;
    int row = slot >> 6, col4 = slot & 63;
    xr[rep] = *(const float4*)(xp + (size_t)row * (BATCH * INF) + col4 * 4);
  }
}

__device__ __forceinline__ void xstore(char* xsb, int tid, const float4 xr[4]) {
#pragma unroll
  for (int rep = 0; rep < 4; ++rep) {
    int slot = rep * 512 + tid;
    int row = slot >> 6, col4 = slot & 63;
    union { bf16 h[4]; ull u; } pk;
    pk.h[0] = (bf16)xr[rep].x; pk.h[1] = (bf16)xr[rep].y;
    pk.h[2] = (bf16)xr[rep].z; pk.h[3] = (bf16)xr[rep].w;
    int byte = (row * (INF * 2) + col4 * 8) ^ ((row & 15) << 4);
    *(ull*)(xsb + byte) = pk.u;
  }
}

// ---------------------------------------------------------------------------
// in-register segmented scan over one chunk (32 t). acc b->s in place.
// ---------------------------------------------------------------------------
__device__ __forceinline__ void reg_scan(f32x4 acc[2][4], float carry[4],
                                         const float la[4], const float l4[4],
                                         int kg, int rl) {
#pragma unroll
  for (int mt = 0; mt < 2; ++mt) {
    float sl[4][4];
#pragma unroll
    for (int nt = 0; nt < 4; ++nt) {
      sl[nt][0] = acc[mt][nt][0];
      sl[nt][1] = fmaf(la[nt], sl[nt][0], acc[mt][nt][1]);
      sl[nt][2] = fmaf(la[nt], sl[nt][1], acc[mt][nt][2]);
      sl[nt][3] = fmaf(la[nt], sl[nt][2], acc[mt][nt][3]);
    }
    float G[4];
#pragma unroll
    for (int nt = 0; nt < 4; ++nt) {
      float g1 = __shfl_up(sl[nt][3], 16);
      G[nt] = (kg >= 1) ? fmaf(l4[nt], g1, sl[nt][3]) : sl[nt][3];
    }
#pragma unroll
    for (int nt = 0; nt < 4; ++nt) {
      float l8 = l4[nt] * l4[nt];
      float g2 = __shfl_up(G[nt], 32);
      G[nt] = (kg >= 2) ? fmaf(l8, g2, G[nt]) : G[nt];
    }
#pragma unroll
    for (int nt = 0; nt < 4; ++nt) {
      float X = __shfl_up(G[nt], 16);
      X = (kg >= 1) ? X : 0.0f;
      float l8 = l4[nt] * l4[nt];
      float p4k = ((kg & 1) ? l4[nt] : 1.0f) * ((kg & 2) ? l8 : 1.0f);
      float cin = fmaf(p4k, carry[nt], X);
      float l2 = la[nt] * la[nt], l3 = l2 * la[nt];
      acc[mt][nt][0] = fmaf(la[nt], cin, sl[nt][0]);
      acc[mt][nt][1] = fmaf(l2, cin, sl[nt][1]);
      acc[mt][nt][2] = fmaf(l3, cin, sl[nt][2]);
      acc[mt][nt][3] = fmaf(l4[nt], cin, sl[nt][3]);
    }
#pragma unroll
    for (int nt = 0; nt < 4; ++nt)
      carry[nt] = __shfl(acc[mt][nt][3], rl + 48);
  }
}

// ---------------------------------------------------------------------------
// GEMM1 with B' streamed from L2 (fallback path only)
// ---------------------------------------------------------------------------
__device__ __forceinline__ void gemm1_l2(const char* xsb, const bf16* __restrict__ Bb,
                                         f32x4 acc[2][4], int n0, int rl, int kg) {
#pragma unroll
  for (int k = 0; k < 8; ++k) {
    bf16x8 af[2], bfr[4];
#pragma unroll
    for (int mt = 0; mt < 2; ++mt) {
      int row = mt * 16 + rl;
      int byte = (row * (INF * 2) + (k * 32 + kg * 8) * 2) ^ (rl << 4);
      af[mt] = *(const bf16x8*)(xsb + byte);
    }
#pragma unroll
    for (int nt = 0; nt < 4; ++nt)
      bfr[nt] = *(const bf16x8*)(Bb + (size_t)(n0 + nt * 16 + rl) * INF + k * 32 + kg * 8);
#pragma unroll
    for (int mt = 0; mt < 2; ++mt)
#pragma unroll
      for (int nt = 0; nt < 4; ++nt)
        acc[mt][nt] = __builtin_amdgcn_mfma_f32_16x16x32_bf16(af[mt], bfr[nt], acc[mt][nt], 0, 0, 0);
  }
}

// ---------------------------------------------------------------------------
// PASS0TN: pass0f-v2 structure (4 single-use xs buffers, 2 barriers, stores
// after barrier) with direct [t][n] row-major bfrag stores (R10-proven parity).
// bfrag row = (cg*32+b)*128 + jj*32 + t, col = n.
// ---------------------------------------------------------------------------
__global__ __launch_bounds__(512, 2)
void k_pass0tn(const float* __restrict__ x, const bf16* __restrict__ Bb,
               const float* __restrict__ lam, float* __restrict__ Z,
               bf16* __restrict__ bfrag) {
  __shared__ __align__(16) char xs[4][CLEN * INF * 2];   // 4x16KB

  const int tid = threadIdx.x, wid = tid >> 6, lane = tid & 63;
  const int rl = lane & 15, kg = lane >> 4;
  const int b = blockIdx.x >> 4, cg = blockIdx.x & 15;
  const int n0 = wid * 64;

  float la[4], l4[4], carry[4];
#pragma unroll
  for (int nt = 0; nt < 4; ++nt) {
    float v = lam[n0 + nt * 16 + rl];
    la[nt] = v; l4[nt] = (v * v) * (v * v);
    carry[nt] = 0.0f;
  }

  bf16x8 Breg[8][4];
#pragma unroll
  for (int k = 0; k < 8; ++k)
#pragma unroll
    for (int nt = 0; nt < 4; ++nt)
      Breg[k][nt] = *(const bf16x8*)(Bb + (size_t)(n0 + nt * 16 + rl) * INF + k * 32 + kg * 8);

  // prologue: stage jobs 0 and 1
  {
    float4 xr[4];
    xload(x + ((size_t)(cg * NJOB * CLEN) * BATCH + b) * INF, tid, xr);
    xstore(xs[0], tid, xr);
    xload(x + ((size_t)((cg * NJOB + 1) * CLEN) * BATCH + b) * INF, tid, xr);
    xstore(xs[1], tid, xr);
  }
  __syncthreads();

#pragma unroll
  for (int jj = 0; jj < NJOB; ++jj) {
    const int c = cg * NJOB + jj;
    f32x4 acc[2][4] = {};
#pragma unroll
    for (int k = 0; k < 8; ++k) {
      bf16x8 af[2];
#pragma unroll
      for (int mt = 0; mt < 2; ++mt) {
        int row = mt * 16 + rl;
        int byte = (row * (INF * 2) + (k * 32 + kg * 8) * 2) ^ (rl << 4);
        af[mt] = *(const bf16x8*)(&xs[jj][0] + byte);
      }
#pragma unroll
      for (int mt = 0; mt < 2; ++mt)
#pragma unroll
        for (int nt = 0; nt < 4; ++nt)
          acc[mt][nt] = __builtin_amdgcn_mfma_f32_16x16x32_bf16(af[mt], Breg[k][nt], acc[mt][nt], 0, 0, 0);
    }

    float4 xr[4];
    if (jj < 2)
      xload(x + ((size_t)((c + 2) * CLEN) * BATCH + b) * INF, tid, xr);

    reg_scan(acc, carry, la, l4, kg, rl);

    if (jj < 2) {
      xstore(xs[jj + 2], tid, xr);
      __syncthreads();           // xs[jj+2] visible for iteration jj+2
    }

    // [t][n] stores AFTER the barrier: drain overlaps next job
    {
      bf16* dstp = bfrag + (((size_t)cg * BATCH + b) * 128 + jj * 32) * NST;
#pragma unroll
      for (int mt = 0; mt < 2; ++mt)
#pragma unroll
        for (int nt = 0; nt < 4; ++nt)
#pragma unroll
          for (int r = 0; r < 4; ++r) {
            int t = mt * 16 + kg * 4 + r;
            int n = n0 + nt * 16 + rl;
            dstp[(size_t)t * NST + n] = (bf16)acc[mt][nt][r];
          }
    }

    if (jj == NJOB - 1) {
      if (kg == 0)
#pragma unroll
        for (int nt = 0; nt < 4; ++nt)
          Z[((size_t)cg * BATCH + b) * NST + n0 + nt * 16 + rl] = carry[nt];
    }
  }
}

// ---------------------------------------------------------------------------
// K3: exclusive prefix over groups: S0[g] = lamG*S0[g-1] + Z[g-1]; writes fin.
// ---------------------------------------------------------------------------
__global__ __launch_bounds__(128)
void k_chain(const float* __restrict__ Z, const float* __restrict__ lamG,
             float* __restrict__ S0, float* __restrict__ fin) {
  const int b = blockIdx.x;
  const int n = blockIdx.y * 128 + threadIdx.x;
  const float lG = lamG[n];
  float z[NCG];
#pragma unroll
  for (int g = 0; g < NCG; ++g)
    z[g] = Z[((size_t)g * BATCH + b) * NST + n];
  float s = 0.0f;
#pragma unroll
  for (int g = 0; g < NCG; ++g) {
    S0[((size_t)g * BATCH + b) * NST + n] = s;
    s = fmaf(lG, s, z[g]);
  }
  fin[(size_t)b * NST + n] = s;
}

// ---------------------------------------------------------------------------
// GEMM2E: per block = (c2 0..31, b): 64 t-rows x 256 o. (gemm2b structure)
// Stage: linear uint4 loads from [t][n] bfrag + fixup via Lam32 table
// (s = s_local + Lam32[dt][n]*S0[n], NO exp2f), swizzled uint4 LDS stores.
// K-loop: A from LDS, C from L2 with software prefetch.
// ---------------------------------------------------------------------------
__global__ __launch_bounds__(512)
void k_gemm2e(const bf16* __restrict__ bfrag, const bf16* __restrict__ Cb,
              const float* __restrict__ S0, const float* __restrict__ Lam32,
              float* __restrict__ out) {
  __shared__ __align__(16) char ss[64 * NST * 2];   // 64 rows x 1KB, XOR swz

  const int tid = threadIdx.x, wid = tid >> 6, lane = tid & 63;
  const int rl = lane & 15, kg = lane >> 4;
  const int c2 = blockIdx.x >> 5, b = blockIdx.x & 31;
  const int cg = c2 >> 1;
  const int dtbase = (c2 & 1) * 64;

  // per-thread n-slice (chunk&63 == tid&63 since 512 % 64 == 0)
  const int n8 = (tid & 63) * 8;
  float s0g[8];
#pragma unroll
  for (int j = 0; j < 8; ++j)
    s0g[j] = S0[((size_t)cg * BATCH + b) * NST + n8 + j];

  // ---- stage 64x512 bf16 tile with table-based fixup
  const uint4* src = (const uint4*)(bfrag +
      (((size_t)cg * BATCH + b) * 128 + dtbase) * NST);
#pragma unroll
  for (int q = 0; q < 8; ++q) {
    int chunk = q * 512 + tid;        // linear 16B chunks of the 64KB tile
    int tl = chunk >> 6;              // row 0..63
    union { uint4 u; bf16 h[8]; } in, ot;
    in.u = src[chunk];
    const float4* lp = (const float4*)(Lam32 + (size_t)(dtbase + tl) * NST + n8);
    float4 L0 = lp[0], L1 = lp[1];
    float lv[8] = {L0.x, L0.y, L0.z, L0.w, L1.x, L1.y, L1.z, L1.w};
#pragma unroll
    for (int j = 0; j < 8; ++j) {
      float s = fmaf(lv[j], s0g[j], (float)in.h[j]);
      ot.h[j] = (bf16)s;
    }
    int byte = (tl * (NST * 2) + (chunk & 63) * 16) ^ ((tl & 15) << 4);
    *(uint4*)(&ss[0] + byte) = ot.u;
  }
  __syncthreads();

  // ---- K-loop: wave owns o-panel [wid*32, +32), all 64 rows; C prefetched
  const int o0 = wid * 32;
  f32x4 acc[4][2] = {};
  bf16x8 cf[2];
#pragma unroll
  for (int ot2 = 0; ot2 < 2; ++ot2)
    cf[ot2] = *(const bf16x8*)(Cb + (size_t)(o0 + ot2 * 16 + rl) * NST + kg * 8);
#pragma unroll
  for (int kq = 0; kq < 16; ++kq) {
    const int k0 = kq * 32;
    bf16x8 cfn[2];
    if (kq < 15)
#pragma unroll
      for (int ot2 = 0; ot2 < 2; ++ot2)
        cfn[ot2] = *(const bf16x8*)(Cb + (size_t)(o0 + ot2 * 16 + rl) * NST + k0 + 32 + kg * 8);
    bf16x8 af[4];
#pragma unroll
    for (int mf = 0; mf < 4; ++mf) {
      int t = mf * 16 + rl;
      af[mf] = *(const bf16x8*)(&ss[0] +
          ((t * (NST * 2) + (k0 + kg * 8) * 2) ^ ((t & 15) << 4)));
    }
#pragma unroll
    for (int mf = 0; mf < 4; ++mf)
#pragma unroll
      for (int ot2 = 0; ot2 < 2; ++ot2)
        acc[mf][ot2] = __builtin_amdgcn_mfma_f32_16x16x32_bf16(af[mf], cf[ot2], acc[mf][ot2], 0, 0, 0);
    if (kq < 15) {
      cf[0] = cfn[0]; cf[1] = cfn[1];
    }
  }

  // ---- epilogue: D row=(lane>>4)*4+reg, col=lane&15
#pragma unroll
  for (int mf = 0; mf < 4; ++mf)
#pragma unroll
    for (int ot2 = 0; ot2 < 2; ++ot2)
#pragma unroll
      for (int r = 0; r < 4; ++r) {
        int ml = mf * 16 + kg * 4 + r;
        size_t srow = (size_t)c2 * 64 + ml;
        int o = o0 + ot2 * 16 + rl;
        out[(srow * BATCH + b) * OUTF + o] = acc[mf][ot2][r];
      }
}

// ---------------------------------------------------------------------------
// Fallback: pass0 (Z only) + fused pass1 (R5-proven ~142us)
// ---------------------------------------------------------------------------
__global__ __launch_bounds__(512, 2)
void k_pass0_fb(const float* __restrict__ x, const bf16* __restrict__ Bb,
                const float* __restrict__ lam, float* __restrict__ Z) {
  __shared__ __align__(16) char xs[2][CLEN * INF * 2];

  const int tid = threadIdx.x, wid = tid >> 6, lane = tid & 63;
  const int rl = lane & 15, kg = lane >> 4;
  const int b = blockIdx.x >> 4, cg = blockIdx.x & 15;
  const int n0 = wid * 64;

  float la[4], l4[4], carry[4];
#pragma unroll
  for (int nt = 0; nt < 4; ++nt) {
    float v = lam[n0 + nt * 16 + rl];
    la[nt] = v; l4[nt] = (v * v) * (v * v);
    carry[nt] = 0.0f;
  }

  bf16x8 Breg[8][4];
#pragma unroll
  for (int k = 0; k < 8; ++k)
#pragma unroll
    for (int nt = 0; nt < 4; ++nt)
      Breg[k][nt] = *(const bf16x8*)(Bb + (size_t)(n0 + nt * 16 + rl) * INF + k * 32 + kg * 8);

  {
    float4 xr0[4];
    xload(x + ((size_t)(cg * NJOB * CLEN) * BATCH + b) * INF, tid, xr0);
    xstore(xs[0], tid, xr0);
  }
  __syncthreads();

#pragma unroll
  for (int jj = 0; jj < NJOB; ++jj) {
    const int c = cg * NJOB + jj;
    f32x4 acc[2][4] = {};
#pragma unroll
    for (int k = 0; k < 8; ++k) {
      bf16x8 af[2];
#pragma unroll
      for (int mt = 0; mt < 2; ++mt) {
        int row = mt * 16 + rl;
        int byte = (row * (INF * 2) + (k * 32 + kg * 8) * 2) ^ (rl << 4);
        af[mt] = *(const bf16x8*)(&xs[jj & 1][0] + byte);
      }
#pragma unroll
      for (int mt = 0; mt < 2; ++mt)
#pragma unroll
        for (int nt = 0; nt < 4; ++nt)
          acc[mt][nt] = __builtin_amdgcn_mfma_f32_16x16x32_bf16(af[mt], Breg[k][nt], acc[mt][nt], 0, 0, 0);
    }

    if (jj < NJOB - 1) {
      float4 xr[4];
      xload(x + ((size_t)((c + 1) * CLEN) * BATCH + b) * INF, tid, xr);
      reg_scan(acc, carry, la, l4, kg, rl);
      xstore(xs[(jj + 1) & 1], tid, xr);
      __syncthreads();
    } else {
      reg_scan(acc, carry, la, l4, kg, rl);
      if (kg == 0)
#pragma unroll
        for (int nt = 0; nt < 4; ++nt)
          Z[((size_t)cg * BATCH + b) * NST + n0 + nt * 16 + rl] = carry[nt];
    }
  }
}

__global__ __launch_bounds__(512)
void k_pass1_fb(const float* __restrict__ x, const bf16* __restrict__ Bb,
                const bf16* __restrict__ Cb, const float* __restrict__ lam,
                const float* __restrict__ S0, float* __restrict__ out,
                float* __restrict__ fin) {
  __shared__ __align__(16) char xs[2][CLEN * INF * 2];
  __shared__ __align__(16) char ss[CLEN * NST * 2];

  const int tid = threadIdx.x, wid = tid >> 6, lane = tid & 63;
  const int rl = lane & 15, kg = lane >> 4;
  const int b = blockIdx.x >> 4, cg = blockIdx.x & 15;
  const int n0 = wid * 64;

  float la[4], l4[4], carry[4];
#pragma unroll
  for (int nt = 0; nt < 4; ++nt) {
    float v = lam[n0 + nt * 16 + rl];
    la[nt] = v; l4[nt] = (v * v) * (v * v);
    carry[nt] = S0[((size_t)cg * BATCH + b) * NST + n0 + nt * 16 + rl];
  }
  {
    float4 xr0[4];
    xload(x + ((size_t)(cg * NJOB * CLEN) * BATCH + b) * INF, tid, xr0);
    xstore(xs[0], tid, xr0);
  }
  __syncthreads();

#pragma unroll
  for (int jj = 0; jj < NJOB; ++jj) {
    const int c = cg * NJOB + jj;
    f32x4 acc[2][4] = {};
    gemm1_l2(&xs[jj & 1][0], Bb, acc, n0, rl, kg);
    {
      float4 xr[4];
      const int lastj = (jj == NJOB - 1);
      if (!lastj)
        xload(x + ((size_t)((c + 1) * CLEN) * BATCH + b) * INF, tid, xr);
      reg_scan(acc, carry, la, l4, kg, rl);
      if (c == NCH - 1 && kg == 0)
#pragma unroll
        for (int nt = 0; nt < 4; ++nt)
          fin[(size_t)b * NST + n0 + nt * 16 + rl] = carry[nt];
      __syncthreads();
#pragma unroll
      for (int mt = 0; mt < 2; ++mt)
#pragma unroll
        for (int nt = 0; nt < 4; ++nt)
#pragma unroll
          for (int r = 0; r < 4; ++r) {
            int t = mt * 16 + kg * 4 + r;
            int n = n0 + nt * 16 + rl;
            int byte = (t * (NST * 2) + n * 2) ^ ((t & 15) << 4);
            *(bf16*)(&ss[0] + byte) = (bf16)acc[mt][nt][r];
          }
      if (!lastj) xstore(xs[(jj + 1) & 1], tid, xr);
    }
    __syncthreads();

    const int o0 = wid * 32;
    f32x4 a2[2][2] = {};
#pragma unroll
    for (int k0 = 0; k0 < NST; k0 += 32) {
      bf16x8 af[2], cf[2];
#pragma unroll
      for (int mt = 0; mt < 2; ++mt) {
        int t = mt * 16 + rl;
        int byte = (t * (NST * 2) + (k0 + kg * 8) * 2) ^ (rl << 4);
        af[mt] = *(const bf16x8*)(&ss[0] + byte);
      }
#pragma unroll
      for (int ot = 0; ot < 2; ++ot)
        cf[ot] = *(const bf16x8*)(Cb + (size_t)(o0 + ot * 16 + rl) * NST + k0 + kg * 8);
#pragma unroll
      for (int mt = 0; mt < 2; ++mt)
#pragma unroll
        for (int ot = 0; ot < 2; ++ot)
          a2[mt][ot] = __builtin_amdgcn_mfma_f32_16x16x32_bf16(af[mt], cf[ot], a2[mt][ot], 0, 0, 0);
    }
#pragma unroll
    for (int mt = 0; mt < 2; ++mt)
#pragma unroll
      for (int ot = 0; ot < 2; ++ot)
#pragma unroll
        for (int r = 0; r < 4; ++r) {
          int t = mt * 16 + kg * 4 + r;
          int o = o0 + ot * 16 + rl;
          out[(((size_t)(c * CLEN + t)) * BATCH + b) * OUTF + o] = a2[mt][ot][r];
        }
  }
}

// ---------------------------------------------------------------------------
extern "C" void kernel_launch(void* const* d_in, const int* in_sizes, int n_in,
                              void* d_out, int out_size, void* d_ws, size_t ws_size,
                              hipStream_t stream) {
  const float* x  = (const float*)d_in[0];
  const float* ll = (const float*)d_in[1];
  const float* Bm = (const float*)d_in[2];
  const float* Cm = (const float*)d_in[3];

  char* ws = (char*)d_ws;
  float* lam   = (float*)(ws);                       // 2048 B
  float* lamG  = (float*)(ws + 2048);                // 2048 B
  float* Lam32 = (float*)(ws + 4096);                // 128*512*4 = 256 KB
  bf16*  Bb    = (bf16*)(ws + 4096 + 262144);
  bf16*  Cb    = (bf16*)((char*)Bb + (size_t)NST * INF * 2);
  float* Z     = (float*)((char*)Cb + (size_t)OUTF * NST * 2);
  float* S0    = (float*)((char*)Z + (size_t)NCG * BATCH * NST * 4);
  bf16*  bfrag = (bf16*)((char*)S0 + (size_t)NCG * BATCH * NST * 4);
  const size_t NEED = ((char*)bfrag - ws) + (size_t)SEQ * BATCH * NST * 2;  // ~70MB

  float* out = (float*)d_out;
  float* fin = out + (size_t)SEQ * BATCH * OUTF;

  k_prep<<<dim3(512), dim3(256), 0, stream>>>(ll, Bm, Cm, lam, lamG, Lam32, Bb, Cb);
  if (ws_size >= NEED) {
    k_pass0tn<<<dim3(NBLK), dim3(512), 0, stream>>>(x, Bb, lam, Z, bfrag);
    k_chain<<<dim3(BATCH, 4), dim3(128), 0, stream>>>(Z, lamG, S0, fin);
    k_gemm2e<<<dim3(1024), dim3(512), 0, stream>>>(bfrag, Cb, S0, Lam32, out);
  } else {
    k_pass0_fb<<<dim3(NBLK), dim3(512), 0, stream>>>(x, Bb, lam, Z);
    k_chain<<<dim3(BATCH, 4), dim3(128), 0, stream>>>(Z, lamG, S0, fin);
    k_pass1_fb<<<dim3(NBLK), dim3(512), 0, stream>>>(x, Bb, Cb, lam, S0, out, fin);
  }
}

// Round 16
// 110.384 us; speedup vs baseline: 4.9652x; 1.0433x over previous
//
#include <hip/hip_runtime.h>

#define SEQ   2048
#define BATCH 32
#define INF   256
#define NST   512
#define OUTF  256
#define CLEN  32
#define NCH   64
#define NJOB  4
#define NCG   (NCH / NJOB)          /* 16 chunk-groups of 128 timesteps */
#define NBLK  (NCG * BATCH)         /* 512 blocks */

typedef __bf16 bf16;
typedef __bf16 bf16x8 __attribute__((ext_vector_type(8)));
typedef float  f32x4  __attribute__((ext_vector_type(4)));
typedef unsigned long long ull;

// ---------------------------------------------------------------------------
// K1: lam=exp(-exp(ll)); lamG=lam^128; LamT[n][dt]=lam_n^(dt+1) (f32, n-major
// so fragment decode reads an aligned float4); B'=gamma*B bf16; C bf16
// ---------------------------------------------------------------------------
__global__ void k_prep(const float* __restrict__ ll,
                       const float* __restrict__ Bm,
                       const float* __restrict__ Cm,
                       float* __restrict__ lam,
                       float* __restrict__ lamG,
                       float* __restrict__ LamT,
                       bf16* __restrict__ Bb,
                       bf16* __restrict__ Cb) {
  int i = blockIdx.x * 256 + threadIdx.x;
  if (i < NST) {
    float e = expf(ll[i]);          // -ln(lambda)
    float lmb = expf(-e);
    lam[i] = lmb;
    float p = lmb;
#pragma unroll
    for (int q = 0; q < 7; ++q) p *= p;    // lambda^128
    lamG[i] = p;
    float ee = lmb;
    for (int dt = 0; dt < 128; ++dt) {     // LamT[i*128+dt] = lambda^(dt+1)
      LamT[(size_t)i * 128 + dt] = ee;
      ee *= lmb;
    }
  }
  if (i < NST * INF) {
    int n = i >> 8;
    float lmb = expf(-expf(ll[n]));
    float g = sqrtf(1.0f - lmb * lmb + 1e-7f);
    Bb[i] = (bf16)(Bm[i] * g);
  }
  if (i < OUTF * NST) {
    Cb[i] = (bf16)(Cm[i]);
  }
}

// ---------------------------------------------------------------------------
// x staging helpers. xs layout: [t][i] bf16, byte = (t*512+i*2) ^ ((t&15)<<4)
// ---------------------------------------------------------------------------
__device__ __forceinline__ void xload(const float* __restrict__ xp, int tid,
                                      float4 xr[4]) {
#pragma unroll
  for (int rep = 0; rep < 4; ++rep) {
    int slot = rep * 512 + tid;
    int row = slot >> 6, col4 = slot & 63;
    xr[rep] = *(const float4*)(xp + (size_t)row * (BATCH * INF) + col4 * 4);
  }
}

__device__ __forceinline__ void xstore(char* xsb, int tid, const float4 xr[4]) {
#pragma unroll
  for (int rep = 0; rep < 4; ++rep) {
    int slot = rep * 512 + tid;
    int row = slot >> 6, col4 = slot & 63;
    union { bf16 h[4]; ull u; } pk;
    pk.h[0] = (bf16)xr[rep].x; pk.h[1] = (bf16)xr[rep].y;
    pk.h[2] = (bf16)xr[rep].z; pk.h[3] = (bf16)xr[rep].w;
    int byte = (row * (INF * 2) + col4 * 8) ^ ((row & 15) << 4);
    *(ull*)(xsb + byte) = pk.u;
  }
}

// ---------------------------------------------------------------------------
// in-register segmented scan over one chunk (32 t). acc b->s in place.
// ---------------------------------------------------------------------------
__device__ __forceinline__ void reg_scan(f32x4 acc[2][4], float carry[4],
                                         const float la[4], const float l4[4],
                                         int kg, int rl) {
#pragma unroll
  for (int mt = 0; mt < 2; ++mt) {
    float sl[4][4];
#pragma unroll
    for (int nt = 0; nt < 4; ++nt) {
      sl[nt][0] = acc[mt][nt][0];
      sl[nt][1] = fmaf(la[nt], sl[nt][0], acc[mt][nt][1]);
      sl[nt][2] = fmaf(la[nt], sl[nt][1], acc[mt][nt][2]);
      sl[nt][3] = fmaf(la[nt], sl[nt][2], acc[mt][nt][3]);
    }
    float G[4];
#pragma unroll
    for (int nt = 0; nt < 4; ++nt) {
      float g1 = __shfl_up(sl[nt][3], 16);
      G[nt] = (kg >= 1) ? fmaf(l4[nt], g1, sl[nt][3]) : sl[nt][3];
    }
#pragma unroll
    for (int nt = 0; nt < 4; ++nt) {
      float l8 = l4[nt] * l4[nt];
      float g2 = __shfl_up(G[nt], 32);
      G[nt] = (kg >= 2) ? fmaf(l8, g2, G[nt]) : G[nt];
    }
#pragma unroll
    for (int nt = 0; nt < 4; ++nt) {
      float X = __shfl_up(G[nt], 16);
      X = (kg >= 1) ? X : 0.0f;
      float l8 = l4[nt] * l4[nt];
      float p4k = ((kg & 1) ? l4[nt] : 1.0f) * ((kg & 2) ? l8 : 1.0f);
      float cin = fmaf(p4k, carry[nt], X);
      float l2 = la[nt] * la[nt], l3 = l2 * la[nt];
      acc[mt][nt][0] = fmaf(la[nt], cin, sl[nt][0]);
      acc[mt][nt][1] = fmaf(l2, cin, sl[nt][1]);
      acc[mt][nt][2] = fmaf(l3, cin, sl[nt][2]);
      acc[mt][nt][3] = fmaf(l4[nt], cin, sl[nt][3]);
    }
#pragma unroll
    for (int nt = 0; nt < 4; ++nt)
      carry[nt] = __shfl(acc[mt][nt][3], rl + 48);
  }
}

// ---------------------------------------------------------------------------
// GEMM1 with B' streamed from L2 (fallback path only)
// ---------------------------------------------------------------------------
__device__ __forceinline__ void gemm1_l2(const char* xsb, const bf16* __restrict__ Bb,
                                         f32x4 acc[2][4], int n0, int rl, int kg) {
#pragma unroll
  for (int k = 0; k < 8; ++k) {
    bf16x8 af[2], bfr[4];
#pragma unroll
    for (int mt = 0; mt < 2; ++mt) {
      int row = mt * 16 + rl;
      int byte = (row * (INF * 2) + (k * 32 + kg * 8) * 2) ^ (rl << 4);
      af[mt] = *(const bf16x8*)(xsb + byte);
    }
#pragma unroll
    for (int nt = 0; nt < 4; ++nt)
      bfr[nt] = *(const bf16x8*)(Bb + (size_t)(n0 + nt * 16 + rl) * INF + k * 32 + kg * 8);
#pragma unroll
    for (int mt = 0; mt < 2; ++mt)
#pragma unroll
      for (int nt = 0; nt < 4; ++nt)
        acc[mt][nt] = __builtin_amdgcn_mfma_f32_16x16x32_bf16(af[mt], bfr[nt], acc[mt][nt], 0, 0, 0);
  }
}

// ---------------------------------------------------------------------------
// PASS0F (R14-proven, 43us): 4 single-use xs buffers; 2 barriers in job loop;
// fragment-native 8B bfrag stores AFTER the barrier.
// bfrag index (8B units): ((((cg*32+b)*4+jj)*8+wid)*8 + mt*4+nt)*64 + lane
// ---------------------------------------------------------------------------
__global__ __launch_bounds__(512, 2)
void k_pass0f(const float* __restrict__ x, const bf16* __restrict__ Bb,
              const float* __restrict__ lam, float* __restrict__ Z,
              ull* __restrict__ bfrag) {
  __shared__ __align__(16) char xs[4][CLEN * INF * 2];   // 4x16KB

  const int tid = threadIdx.x, wid = tid >> 6, lane = tid & 63;
  const int rl = lane & 15, kg = lane >> 4;
  const int b = blockIdx.x >> 4, cg = blockIdx.x & 15;
  const int n0 = wid * 64;

  float la[4], l4[4], carry[4];
#pragma unroll
  for (int nt = 0; nt < 4; ++nt) {
    float v = lam[n0 + nt * 16 + rl];
    la[nt] = v; l4[nt] = (v * v) * (v * v);
    carry[nt] = 0.0f;
  }

  bf16x8 Breg[8][4];
#pragma unroll
  for (int k = 0; k < 8; ++k)
#pragma unroll
    for (int nt = 0; nt < 4; ++nt)
      Breg[k][nt] = *(const bf16x8*)(Bb + (size_t)(n0 + nt * 16 + rl) * INF + k * 32 + kg * 8);

  // prologue: stage jobs 0 and 1
  {
    float4 xr[4];
    xload(x + ((size_t)(cg * NJOB * CLEN) * BATCH + b) * INF, tid, xr);
    xstore(xs[0], tid, xr);
    xload(x + ((size_t)((cg * NJOB + 1) * CLEN) * BATCH + b) * INF, tid, xr);
    xstore(xs[1], tid, xr);
  }
  __syncthreads();

#pragma unroll
  for (int jj = 0; jj < NJOB; ++jj) {
    const int c = cg * NJOB + jj;
    f32x4 acc[2][4] = {};
#pragma unroll
    for (int k = 0; k < 8; ++k) {
      bf16x8 af[2];
#pragma unroll
      for (int mt = 0; mt < 2; ++mt) {
        int row = mt * 16 + rl;
        int byte = (row * (INF * 2) + (k * 32 + kg * 8) * 2) ^ (rl << 4);
        af[mt] = *(const bf16x8*)(&xs[jj][0] + byte);
      }
#pragma unroll
      for (int mt = 0; mt < 2; ++mt)
#pragma unroll
        for (int nt = 0; nt < 4; ++nt)
          acc[mt][nt] = __builtin_amdgcn_mfma_f32_16x16x32_bf16(af[mt], Breg[k][nt], acc[mt][nt], 0, 0, 0);
    }

    float4 xr[4];
    if (jj < 2)
      xload(x + ((size_t)((c + 2) * CLEN) * BATCH + b) * INF, tid, xr);

    reg_scan(acc, carry, la, l4, kg, rl);

    if (jj < 2) {
      xstore(xs[jj + 2], tid, xr);
      __syncthreads();           // xs[jj+2] visible for iteration jj+2
    }

    // fragment-native stores AFTER the barrier: drain overlaps next job
    {
      ull* dst = bfrag + ((size_t)(((cg * BATCH + b) * NJOB + jj) * 8 + wid)) * 512 + lane;
#pragma unroll
      for (int mt = 0; mt < 2; ++mt)
#pragma unroll
        for (int nt = 0; nt < 4; ++nt) {
          union { bf16 h[4]; ull u; } pk;
          pk.h[0] = (bf16)acc[mt][nt][0];
          pk.h[1] = (bf16)acc[mt][nt][1];
          pk.h[2] = (bf16)acc[mt][nt][2];
          pk.h[3] = (bf16)acc[mt][nt][3];
          dst[(mt * 4 + nt) * 64] = pk.u;
        }
    }

    if (jj == NJOB - 1) {
      if (kg == 0)
#pragma unroll
        for (int nt = 0; nt < 4; ++nt)
          Z[((size_t)cg * BATCH + b) * NST + n0 + nt * 16 + rl] = carry[nt];
    }
  }
}

// ---------------------------------------------------------------------------
// K3: exclusive prefix over groups: S0[g] = lamG*S0[g-1] + Z[g-1]; writes fin.
// ---------------------------------------------------------------------------
__global__ __launch_bounds__(128)
void k_chain(const float* __restrict__ Z, const float* __restrict__ lamG,
             float* __restrict__ S0, float* __restrict__ fin) {
  const int b = blockIdx.x;
  const int n = blockIdx.y * 128 + threadIdx.x;
  const float lG = lamG[n];
  float z[NCG];
#pragma unroll
  for (int g = 0; g < NCG; ++g)
    z[g] = Z[((size_t)g * BATCH + b) * NST + n];
  float s = 0.0f;
#pragma unroll
  for (int g = 0; g < NCG; ++g) {
    S0[((size_t)g * BATCH + b) * NST + n] = s;
    s = fmaf(lG, s, z[g]);
  }
  fin[(size_t)b * NST + n] = s;
}

// ---------------------------------------------------------------------------
// GEMM2F: per block = (c2 0..31, b): 64 t-rows x 256 o.
// Stage from fragment-layout bfrag + LamT float4 fixup (no exp2f).
// K-loop: A from swizzled LDS, C from L2 with DEPTH-3 rolling prefetch.
// ---------------------------------------------------------------------------
__global__ __launch_bounds__(512)
void k_gemm2f(const ull* __restrict__ bfrag, const bf16* __restrict__ Cb,
              const float* __restrict__ S0, const float* __restrict__ LamT,
              float* __restrict__ out) {
  __shared__ __align__(16) char ss[64 * NST * 2];   // 64 rows x 1KB, XOR swz

  const int tid = threadIdx.x, wid = tid >> 6, lane = tid & 63;
  const int rl = lane & 15, kg = lane >> 4;
  const int c2 = blockIdx.x >> 5, b = blockIdx.x & 31;
  const int cg = c2 >> 1;

  // ---- stage: 8192 8B chunks (2 jobs x 4096), 16 per thread
  const ull* src8 = bfrag +
      ((size_t)((cg * BATCH + b) * NJOB + (c2 & 1) * 2)) * 4096;
  const float* S0g = S0 + ((size_t)cg * BATCH + b) * NST;
#pragma unroll
  for (int q = 0; q < 16; ++q) {
    int chunk = q * 512 + tid;
    int jjh = chunk >> 12;
    int within = chunk & 4095;
    int widx = within >> 9;
    int fr = (within >> 6) & 7;
    int mt = fr >> 2, nt = fr & 3;
    int ls = within & 63;
    int kgs = ls >> 4, rls = ls & 15;
    int n = widx * 64 + nt * 16 + rls;
    int t0 = jjh * 32 + mt * 16 + kgs * 4;         // row within 64-tile
    int dt0 = (c2 & 1) * 64 + t0;                  // row within 128-group

    union { ull u; bf16 h[4]; } in;
    in.u = src8[chunk];
    float4 Lv = *(const float4*)(LamT + (size_t)n * 128 + dt0);  // lam^(dt0+1..+4)
    float s0 = S0g[n];
    float lv[4] = {Lv.x, Lv.y, Lv.z, Lv.w};
#pragma unroll
    for (int r = 0; r < 4; ++r) {
      float s = fmaf(lv[r], s0, (float)in.h[r]);
      int t = t0 + r;
      int byte = (t * (NST * 2) + n * 2) ^ ((t & 15) << 4);
      *(bf16*)(&ss[0] + byte) = (bf16)s;
    }
  }
  __syncthreads();

  // ---- K-loop: wave owns o-panel [wid*32, +32); C prefetch depth 3
  const int o0 = wid * 32;
  f32x4 acc[4][2] = {};
  bf16x8 cfp0[2], cfp1[2], cfp2[2];

#define LOADC(CF, KQ) { \
    CF[0] = *(const bf16x8*)(Cb + (size_t)(o0 + rl) * NST + (KQ) * 32 + kg * 8); \
    CF[1] = *(const bf16x8*)(Cb + (size_t)(o0 + 16 + rl) * NST + (KQ) * 32 + kg * 8); }
#define G2STEP(KQ, CF) { \
    bf16x8 af0, af1, af2, af3; \
    { int t = rl;      af0 = *(const bf16x8*)(&ss[0] + ((t * (NST*2) + ((KQ)*32 + kg*8)*2) ^ ((t & 15) << 4))); } \
    { int t = 16 + rl; af1 = *(const bf16x8*)(&ss[0] + ((t * (NST*2) + ((KQ)*32 + kg*8)*2) ^ ((t & 15) << 4))); } \
    { int t = 32 + rl; af2 = *(const bf16x8*)(&ss[0] + ((t * (NST*2) + ((KQ)*32 + kg*8)*2) ^ ((t & 15) << 4))); } \
    { int t = 48 + rl; af3 = *(const bf16x8*)(&ss[0] + ((t * (NST*2) + ((KQ)*32 + kg*8)*2) ^ ((t & 15) << 4))); } \
    acc[0][0] = __builtin_amdgcn_mfma_f32_16x16x32_bf16(af0, CF[0], acc[0][0], 0,0,0); \
    acc[0][1] = __builtin_amdgcn_mfma_f32_16x16x32_bf16(af0, CF[1], acc[0][1], 0,0,0); \
    acc[1][0] = __builtin_amdgcn_mfma_f32_16x16x32_bf16(af1, CF[0], acc[1][0], 0,0,0); \
    acc[1][1] = __builtin_amdgcn_mfma_f32_16x16x32_bf16(af1, CF[1], acc[1][1], 0,0,0); \
    acc[2][0] = __builtin_amdgcn_mfma_f32_16x16x32_bf16(af2, CF[0], acc[2][0], 0,0,0); \
    acc[2][1] = __builtin_amdgcn_mfma_f32_16x16x32_bf16(af2, CF[1], acc[2][1], 0,0,0); \
    acc[3][0] = __builtin_amdgcn_mfma_f32_16x16x32_bf16(af3, CF[0], acc[3][0], 0,0,0); \
    acc[3][1] = __builtin_amdgcn_mfma_f32_16x16x32_bf16(af3, CF[1], acc[3][1], 0,0,0); }

  LOADC(cfp0, 0) LOADC(cfp1, 1) LOADC(cfp2, 2)
  G2STEP(0,  cfp0) LOADC(cfp0, 3)
  G2STEP(1,  cfp1) LOADC(cfp1, 4)
  G2STEP(2,  cfp2) LOADC(cfp2, 5)
  G2STEP(3,  cfp0) LOADC(cfp0, 6)
  G2STEP(4,  cfp1) LOADC(cfp1, 7)
  G2STEP(5,  cfp2) LOADC(cfp2, 8)
  G2STEP(6,  cfp0) LOADC(cfp0, 9)
  G2STEP(7,  cfp1) LOADC(cfp1, 10)
  G2STEP(8,  cfp2) LOADC(cfp2, 11)
  G2STEP(9,  cfp0) LOADC(cfp0, 12)
  G2STEP(10, cfp1) LOADC(cfp1, 13)
  G2STEP(11, cfp2) LOADC(cfp2, 14)
  G2STEP(12, cfp0) LOADC(cfp0, 15)
  G2STEP(13, cfp1)
  G2STEP(14, cfp2)
  G2STEP(15, cfp0)
#undef G2STEP
#undef LOADC

  // ---- epilogue: D row=(lane>>4)*4+reg, col=lane&15
#pragma unroll
  for (int mf = 0; mf < 4; ++mf)
#pragma unroll
    for (int ot2 = 0; ot2 < 2; ++ot2)
#pragma unroll
      for (int r = 0; r < 4; ++r) {
        int ml = mf * 16 + kg * 4 + r;
        size_t srow = (size_t)c2 * 64 + ml;
        int o = o0 + ot2 * 16 + rl;
        out[(srow * BATCH + b) * OUTF + o] = acc[mf][ot2][r];
      }
}

// ---------------------------------------------------------------------------
// Fallback: pass0 (Z only) + fused pass1 (R5-proven ~142us)
// ---------------------------------------------------------------------------
__global__ __launch_bounds__(512, 2)
void k_pass0_fb(const float* __restrict__ x, const bf16* __restrict__ Bb,
                const float* __restrict__ lam, float* __restrict__ Z) {
  __shared__ __align__(16) char xs[2][CLEN * INF * 2];

  const int tid = threadIdx.x, wid = tid >> 6, lane = tid & 63;
  const int rl = lane & 15, kg = lane >> 4;
  const int b = blockIdx.x >> 4, cg = blockIdx.x & 15;
  const int n0 = wid * 64;

  float la[4], l4[4], carry[4];
#pragma unroll
  for (int nt = 0; nt < 4; ++nt) {
    float v = lam[n0 + nt * 16 + rl];
    la[nt] = v; l4[nt] = (v * v) * (v * v);
    carry[nt] = 0.0f;
  }

  bf16x8 Breg[8][4];
#pragma unroll
  for (int k = 0; k < 8; ++k)
#pragma unroll
    for (int nt = 0; nt < 4; ++nt)
      Breg[k][nt] = *(const bf16x8*)(Bb + (size_t)(n0 + nt * 16 + rl) * INF + k * 32 + kg * 8);

  {
    float4 xr0[4];
    xload(x + ((size_t)(cg * NJOB * CLEN) * BATCH + b) * INF, tid, xr0);
    xstore(xs[0], tid, xr0);
  }
  __syncthreads();

#pragma unroll
  for (int jj = 0; jj < NJOB; ++jj) {
    const int c = cg * NJOB + jj;
    f32x4 acc[2][4] = {};
#pragma unroll
    for (int k = 0; k < 8; ++k) {
      bf16x8 af[2];
#pragma unroll
      for (int mt = 0; mt < 2; ++mt) {
        int row = mt * 16 + rl;
        int byte = (row * (INF * 2) + (k * 32 + kg * 8) * 2) ^ (rl << 4);
        af[mt] = *(const bf16x8*)(&xs[jj & 1][0] + byte);
      }
#pragma unroll
      for (int mt = 0; mt < 2; ++mt)
#pragma unroll
        for (int nt = 0; nt < 4; ++nt)
          acc[mt][nt] = __builtin_amdgcn_mfma_f32_16x16x32_bf16(af[mt], Breg[k][nt], acc[mt][nt], 0, 0, 0);
    }

    if (jj < NJOB - 1) {
      float4 xr[4];
      xload(x + ((size_t)((c + 1) * CLEN) * BATCH + b) * INF, tid, xr);
      reg_scan(acc, carry, la, l4, kg, rl);
      xstore(xs[(jj + 1) & 1], tid, xr);
      __syncthreads();
    } else {
      reg_scan(acc, carry, la, l4, kg, rl);
      if (kg == 0)
#pragma unroll
        for (int nt = 0; nt < 4; ++nt)
          Z[((size_t)cg * BATCH + b) * NST + n0 + nt * 16 + rl] = carry[nt];
    }
  }
}

__global__ __launch_bounds__(512)
void k_pass1_fb(const float* __restrict__ x, const bf16* __restrict__ Bb,
                const bf16* __restrict__ Cb, const float* __restrict__ lam,
                const float* __restrict__ S0, float* __restrict__ out,
                float* __restrict__ fin) {
  __shared__ __align__(16) char xs[2][CLEN * INF * 2];
  __shared__ __align__(16) char ss[CLEN * NST * 2];

  const int tid = threadIdx.x, wid = tid >> 6, lane = tid & 63;
  const int rl = lane & 15, kg = lane >> 4;
  const int b = blockIdx.x >> 4, cg = blockIdx.x & 15;
  const int n0 = wid * 64;

  float la[4], l4[4], carry[4];
#pragma unroll
  for (int nt = 0; nt < 4; ++nt) {
    float v = lam[n0 + nt * 16 + rl];
    la[nt] = v; l4[nt] = (v * v) * (v * v);
    carry[nt] = S0[((size_t)cg * BATCH + b) * NST + n0 + nt * 16 + rl];
  }
  {
    float4 xr0[4];
    xload(x + ((size_t)(cg * NJOB * CLEN) * BATCH + b) * INF, tid, xr0);
    xstore(xs[0], tid, xr0);
  }
  __syncthreads();

#pragma unroll
  for (int jj = 0; jj < NJOB; ++jj) {
    const int c = cg * NJOB + jj;
    f32x4 acc[2][4] = {};
    gemm1_l2(&xs[jj & 1][0], Bb, acc, n0, rl, kg);
    {
      float4 xr[4];
      const int lastj = (jj == NJOB - 1);
      if (!lastj)
        xload(x + ((size_t)((c + 1) * CLEN) * BATCH + b) * INF, tid, xr);
      reg_scan(acc, carry, la, l4, kg, rl);
      if (c == NCH - 1 && kg == 0)
#pragma unroll
        for (int nt = 0; nt < 4; ++nt)
          fin[(size_t)b * NST + n0 + nt * 16 + rl] = carry[nt];
      __syncthreads();
#pragma unroll
      for (int mt = 0; mt < 2; ++mt)
#pragma unroll
        for (int nt = 0; nt < 4; ++nt)
#pragma unroll
          for (int r = 0; r < 4; ++r) {
            int t = mt * 16 + kg * 4 + r;
            int n = n0 + nt * 16 + rl;
            int byte = (t * (NST * 2) + n * 2) ^ ((t & 15) << 4);
            *(bf16*)(&ss[0] + byte) = (bf16)acc[mt][nt][r];
          }
      if (!lastj) xstore(xs[(jj + 1) & 1], tid, xr);
    }
    __syncthreads();

    const int o0 = wid * 32;
    f32x4 a2[2][2] = {};
#pragma unroll
    for (int k0 = 0; k0 < NST; k0 += 32) {
      bf16x8 af[2], cf[2];
#pragma unroll
      for (int mt = 0; mt < 2; ++mt) {
        int t = mt * 16 + rl;
        int byte = (t * (NST * 2) + (k0 + kg * 8) * 2) ^ (rl << 4);
        af[mt] = *(const bf16x8*)(&ss[0] + byte);
      }
#pragma unroll
      for (int ot = 0; ot < 2; ++ot)
        cf[ot] = *(const bf16x8*)(Cb + (size_t)(o0 + ot * 16 + rl) * NST + k0 + kg * 8);
#pragma unroll
      for (int mt = 0; mt < 2; ++mt)
#pragma unroll
        for (int ot = 0; ot < 2; ++ot)
          a2[mt][ot] = __builtin_amdgcn_mfma_f32_16x16x32_bf16(af[mt], cf[ot], a2[mt][ot], 0, 0, 0);
    }
#pragma unroll
    for (int mt = 0; mt < 2; ++mt)
#pragma unroll
      for (int ot = 0; ot < 2; ++ot)
#pragma unroll
        for (int r = 0; r < 4; ++r) {
          int t = mt * 16 + kg * 4 + r;
          int o = o0 + ot * 16 + rl;
          out[(((size_t)(c * CLEN + t)) * BATCH + b) * OUTF + o] = a2[mt][ot][r];
        }
  }
}

// ---------------------------------------------------------------------------
extern "C" void kernel_launch(void* const* d_in, const int* in_sizes, int n_in,
                              void* d_out, int out_size, void* d_ws, size_t ws_size,
                              hipStream_t stream) {
  const float* x  = (const float*)d_in[0];
  const float* ll = (const float*)d_in[1];
  const float* Bm = (const float*)d_in[2];
  const float* Cm = (const float*)d_in[3];

  char* ws = (char*)d_ws;
  float* lam  = (float*)(ws);                        // 2048 B
  float* lamG = (float*)(ws + 2048);                 // 2048 B
  float* LamT = (float*)(ws + 4096);                 // 512*128*4 = 256 KB
  bf16*  Bb   = (bf16*)(ws + 4096 + 262144);
  bf16*  Cb   = (bf16*)((char*)Bb + (size_t)NST * INF * 2);
  float* Z    = (float*)((char*)Cb + (size_t)OUTF * NST * 2);
  float* S0   = (float*)((char*)Z + (size_t)NCG * BATCH * NST * 4);
  ull*   bfrag= (ull*)((char*)S0 + (size_t)NCG * BATCH * NST * 4);
  const size_t NEED = ((char*)bfrag - ws) + (size_t)SEQ * BATCH * NST * 2;  // ~70MB

  float* out = (float*)d_out;
  float* fin = out + (size_t)SEQ * BATCH * OUTF;

  k_prep<<<dim3(512), dim3(256), 0, stream>>>(ll, Bm, Cm, lam, lamG, LamT, Bb, Cb);
  if (ws_size >= NEED) {
    k_pass0f<<<dim3(NBLK), dim3(512), 0, stream>>>(x, Bb, lam, Z, bfrag);
    k_chain<<<dim3(BATCH, 4), dim3(128), 0, stream>>>(Z, lamG, S0, fin);
    k_gemm2f<<<dim3(1024), dim3(512), 0, stream>>>(bfrag, Cb, S0, LamT, out);
  } else {
    k_pass0_fb<<<dim3(NBLK), dim3(512), 0, stream>>>(x, Bb, lam, Z);
    k_chain<<<dim3(BATCH, 4), dim3(128), 0, stream>>>(Z, lamG, S0, fin);
    k_pass1_fb<<<dim3(NBLK), dim3(512), 0, stream>>>(x, Bb, Cb, lam, S0, out, fin);
  }
}

// Round 17
// 97.982 us; speedup vs baseline: 5.5937x; 1.1266x over previous
//
#include <hip/hip_runtime.h>

#define SEQ   2048
#define BATCH 32
#define INF   256
#define NST   512
#define OUTF  256
#define CLEN  32
#define NCH   64
#define NJOB  4
#define NCG   (NCH / NJOB)          /* 16 chunk-groups of 128 timesteps */
#define NBLK  (NCG * BATCH)         /* 512 blocks */

typedef __bf16 bf16;
typedef __bf16 bf16x8 __attribute__((ext_vector_type(8)));
typedef float  f32x4  __attribute__((ext_vector_type(4)));
typedef unsigned long long ull;

// ---------------------------------------------------------------------------
// K1: lam=exp(-exp(ll)); lamG=lam^128; l2la=log2(lam); B'=gamma*B bf16; C bf16
// ---------------------------------------------------------------------------
__global__ void k_prep(const float* __restrict__ ll,
                       const float* __restrict__ Bm,
                       const float* __restrict__ Cm,
                       float* __restrict__ lam,
                       float* __restrict__ lamG,
                       float* __restrict__ l2la,
                       bf16* __restrict__ Bb,
                       bf16* __restrict__ Cb) {
  int i = blockIdx.x * 256 + threadIdx.x;
  if (i < NST) {
    float e = expf(ll[i]);          // -ln(lambda)
    float lmb = expf(-e);
    lam[i] = lmb;
    l2la[i] = -e * 1.44269504088896341f;   // log2(lambda)
    float p = lmb;
#pragma unroll
    for (int q = 0; q < 7; ++q) p *= p;    // lambda^128
    lamG[i] = p;
  }
  if (i < NST * INF) {
    int n = i >> 8;
    float lmb = expf(-expf(ll[n]));
    float g = sqrtf(1.0f - lmb * lmb + 1e-7f);
    Bb[i] = (bf16)(Bm[i] * g);
  }
  if (i < OUTF * NST) {
    Cb[i] = (bf16)(Cm[i]);
  }
}

// ---------------------------------------------------------------------------
// x staging helpers. xs layout: [t][i] bf16, byte = (t*512+i*2) ^ ((t&15)<<4)
// ---------------------------------------------------------------------------
__device__ __forceinline__ void xload(const float* __restrict__ xp, int tid,
                                      float4 xr[4]) {
#pragma unroll
  for (int rep = 0; rep < 4; ++rep) {
    int slot = rep * 512 + tid;
    int row = slot >> 6, col4 = slot & 63;
    xr[rep] = *(const float4*)(xp + (size_t)row * (BATCH * INF) + col4 * 4);
  }
}

__device__ __forceinline__ void xstore(char* xsb, int tid, const float4 xr[4]) {
#pragma unroll
  for (int rep = 0; rep < 4; ++rep) {
    int slot = rep * 512 + tid;
    int row = slot >> 6, col4 = slot & 63;
    union { bf16 h[4]; ull u; } pk;
    pk.h[0] = (bf16)xr[rep].x; pk.h[1] = (bf16)xr[rep].y;
    pk.h[2] = (bf16)xr[rep].z; pk.h[3] = (bf16)xr[rep].w;
    int byte = (row * (INF * 2) + col4 * 8) ^ ((row & 15) << 4);
    *(ull*)(xsb + byte) = pk.u;
  }
}

// ---------------------------------------------------------------------------
// in-register segmented scan over one chunk (32 t). acc b->s in place.
// ---------------------------------------------------------------------------
__device__ __forceinline__ void reg_scan(f32x4 acc[2][4], float carry[4],
                                         const float la[4], const float l4[4],
                                         int kg, int rl) {
#pragma unroll
  for (int mt = 0; mt < 2; ++mt) {
    float sl[4][4];
#pragma unroll
    for (int nt = 0; nt < 4; ++nt) {
      sl[nt][0] = acc[mt][nt][0];
      sl[nt][1] = fmaf(la[nt], sl[nt][0], acc[mt][nt][1]);
      sl[nt][2] = fmaf(la[nt], sl[nt][1], acc[mt][nt][2]);
      sl[nt][3] = fmaf(la[nt], sl[nt][2], acc[mt][nt][3]);
    }
    float G[4];
#pragma unroll
    for (int nt = 0; nt < 4; ++nt) {
      float g1 = __shfl_up(sl[nt][3], 16);
      G[nt] = (kg >= 1) ? fmaf(l4[nt], g1, sl[nt][3]) : sl[nt][3];
    }
#pragma unroll
    for (int nt = 0; nt < 4; ++nt) {
      float l8 = l4[nt] * l4[nt];
      float g2 = __shfl_up(G[nt], 32);
      G[nt] = (kg >= 2) ? fmaf(l8, g2, G[nt]) : G[nt];
    }
#pragma unroll
    for (int nt = 0; nt < 4; ++nt) {
      float X = __shfl_up(G[nt], 16);
      X = (kg >= 1) ? X : 0.0f;
      float l8 = l4[nt] * l4[nt];
      float p4k = ((kg & 1) ? l4[nt] : 1.0f) * ((kg & 2) ? l8 : 1.0f);
      float cin = fmaf(p4k, carry[nt], X);
      float l2 = la[nt] * la[nt], l3 = l2 * la[nt];
      acc[mt][nt][0] = fmaf(la[nt], cin, sl[nt][0]);
      acc[mt][nt][1] = fmaf(l2, cin, sl[nt][1]);
      acc[mt][nt][2] = fmaf(l3, cin, sl[nt][2]);
      acc[mt][nt][3] = fmaf(l4[nt], cin, sl[nt][3]);
    }
#pragma unroll
    for (int nt = 0; nt < 4; ++nt)
      carry[nt] = __shfl(acc[mt][nt][3], rl + 48);
  }
}

// ---------------------------------------------------------------------------
// GEMM1 with B' streamed from L2 (fallback path only)
// ---------------------------------------------------------------------------
__device__ __forceinline__ void gemm1_l2(const char* xsb, const bf16* __restrict__ Bb,
                                         f32x4 acc[2][4], int n0, int rl, int kg) {
#pragma unroll
  for (int k = 0; k < 8; ++k) {
    bf16x8 af[2], bfr[4];
#pragma unroll
    for (int mt = 0; mt < 2; ++mt) {
      int row = mt * 16 + rl;
      int byte = (row * (INF * 2) + (k * 32 + kg * 8) * 2) ^ (rl << 4);
      af[mt] = *(const bf16x8*)(xsb + byte);
    }
#pragma unroll
    for (int nt = 0; nt < 4; ++nt)
      bfr[nt] = *(const bf16x8*)(Bb + (size_t)(n0 + nt * 16 + rl) * INF + k * 32 + kg * 8);
#pragma unroll
    for (int mt = 0; mt < 2; ++mt)
#pragma unroll
      for (int nt = 0; nt < 4; ++nt)
        acc[mt][nt] = __builtin_amdgcn_mfma_f32_16x16x32_bf16(af[mt], bfr[nt], acc[mt][nt], 0, 0, 0);
  }
}

// ---------------------------------------------------------------------------
// PASS0F (R14/R16-proven, 43us): 4 single-use xs buffers; 2 barriers in job
// loop; fragment-native 8B bfrag stores AFTER the barrier.
// bfrag index (8B units): ((((cg*32+b)*4+jj)*8+wid)*8 + mt*4+nt)*64 + lane
// ---------------------------------------------------------------------------
__global__ __launch_bounds__(512, 2)
void k_pass0f(const float* __restrict__ x, const bf16* __restrict__ Bb,
              const float* __restrict__ lam, float* __restrict__ Z,
              ull* __restrict__ bfrag) {
  __shared__ __align__(16) char xs[4][CLEN * INF * 2];   // 4x16KB

  const int tid = threadIdx.x, wid = tid >> 6, lane = tid & 63;
  const int rl = lane & 15, kg = lane >> 4;
  const int b = blockIdx.x >> 4, cg = blockIdx.x & 15;
  const int n0 = wid * 64;

  float la[4], l4[4], carry[4];
#pragma unroll
  for (int nt = 0; nt < 4; ++nt) {
    float v = lam[n0 + nt * 16 + rl];
    la[nt] = v; l4[nt] = (v * v) * (v * v);
    carry[nt] = 0.0f;
  }

  bf16x8 Breg[8][4];
#pragma unroll
  for (int k = 0; k < 8; ++k)
#pragma unroll
    for (int nt = 0; nt < 4; ++nt)
      Breg[k][nt] = *(const bf16x8*)(Bb + (size_t)(n0 + nt * 16 + rl) * INF + k * 32 + kg * 8);

  // prologue: stage jobs 0 and 1
  {
    float4 xr[4];
    xload(x + ((size_t)(cg * NJOB * CLEN) * BATCH + b) * INF, tid, xr);
    xstore(xs[0], tid, xr);
    xload(x + ((size_t)((cg * NJOB + 1) * CLEN) * BATCH + b) * INF, tid, xr);
    xstore(xs[1], tid, xr);
  }
  __syncthreads();

#pragma unroll
  for (int jj = 0; jj < NJOB; ++jj) {
    const int c = cg * NJOB + jj;
    f32x4 acc[2][4] = {};
#pragma unroll
    for (int k = 0; k < 8; ++k) {
      bf16x8 af[2];
#pragma unroll
      for (int mt = 0; mt < 2; ++mt) {
        int row = mt * 16 + rl;
        int byte = (row * (INF * 2) + (k * 32 + kg * 8) * 2) ^ (rl << 4);
        af[mt] = *(const bf16x8*)(&xs[jj][0] + byte);
      }
#pragma unroll
      for (int mt = 0; mt < 2; ++mt)
#pragma unroll
        for (int nt = 0; nt < 4; ++nt)
          acc[mt][nt] = __builtin_amdgcn_mfma_f32_16x16x32_bf16(af[mt], Breg[k][nt], acc[mt][nt], 0, 0, 0);
    }

    float4 xr[4];
    if (jj < 2)
      xload(x + ((size_t)((c + 2) * CLEN) * BATCH + b) * INF, tid, xr);

    reg_scan(acc, carry, la, l4, kg, rl);

    if (jj < 2) {
      xstore(xs[jj + 2], tid, xr);
      __syncthreads();           // xs[jj+2] visible for iteration jj+2
    }

    // fragment-native stores AFTER the barrier: drain overlaps next job
    {
      ull* dst = bfrag + ((size_t)(((cg * BATCH + b) * NJOB + jj) * 8 + wid)) * 512 + lane;
#pragma unroll
      for (int mt = 0; mt < 2; ++mt)
#pragma unroll
        for (int nt = 0; nt < 4; ++nt) {
          union { bf16 h[4]; ull u; } pk;
          pk.h[0] = (bf16)acc[mt][nt][0];
          pk.h[1] = (bf16)acc[mt][nt][1];
          pk.h[2] = (bf16)acc[mt][nt][2];
          pk.h[3] = (bf16)acc[mt][nt][3];
          dst[(mt * 4 + nt) * 64] = pk.u;
        }
    }

    if (jj == NJOB - 1) {
      if (kg == 0)
#pragma unroll
        for (int nt = 0; nt < 4; ++nt)
          Z[((size_t)cg * BATCH + b) * NST + n0 + nt * 16 + rl] = carry[nt];
    }
  }
}

// ---------------------------------------------------------------------------
// K3: exclusive prefix over groups: S0[g] = lamG*S0[g-1] + Z[g-1]; writes fin.
// ---------------------------------------------------------------------------
__global__ __launch_bounds__(128)
void k_chain(const float* __restrict__ Z, const float* __restrict__ lamG,
             float* __restrict__ S0, float* __restrict__ fin) {
  const int b = blockIdx.x;
  const int n = blockIdx.y * 128 + threadIdx.x;
  const float lG = lamG[n];
  float z[NCG];
#pragma unroll
  for (int g = 0; g < NCG; ++g)
    z[g] = Z[((size_t)g * BATCH + b) * NST + n];
  float s = 0.0f;
#pragma unroll
  for (int g = 0; g < NCG; ++g) {
    S0[((size_t)g * BATCH + b) * NST + n] = s;
    s = fmaf(lG, s, z[g]);
  }
  fin[(size_t)b * NST + n] = s;
}

// ---------------------------------------------------------------------------
// GEMM2G: gemm2c (R12-proven, 49us) + depth-1 C prefetch ONLY.
// Per block = (c2 0..31, b): 64 t-rows x 256 o. Fragment stage, exp2f fixup,
// swizzled ss; K-loop A from LDS, C from L2 with 1-step rolling prefetch.
// ---------------------------------------------------------------------------
__global__ __launch_bounds__(512)
void k_gemm2g(const ull* __restrict__ bfrag, const bf16* __restrict__ Cb,
              const float* __restrict__ S0, const float* __restrict__ l2la,
              float* __restrict__ out) {
  __shared__ __align__(16) char ss[64 * NST * 2];   // 64 rows x 1KB, XOR swz

  const int tid = threadIdx.x, wid = tid >> 6, lane = tid & 63;
  const int rl = lane & 15, kg = lane >> 4;
  const int c2 = blockIdx.x >> 5, b = blockIdx.x & 31;
  const int cg = c2 >> 1;

  // ---- stage: 8192 8B chunks (2 jobs x 4096), 16 per thread
  const ull* src8 = bfrag +
      ((size_t)((cg * BATCH + b) * NJOB + (c2 & 1) * 2)) * 4096;
  const float* S0g = S0 + ((size_t)cg * BATCH + b) * NST;
#pragma unroll
  for (int q = 0; q < 16; ++q) {
    int chunk = q * 512 + tid;
    int jjh = chunk >> 12;
    int within = chunk & 4095;
    int widx = within >> 9;
    int fr = (within >> 6) & 7;
    int mt = fr >> 2, nt = fr & 3;
    int ls = within & 63;
    int kgs = ls >> 4, rls = ls & 15;
    int n = widx * 64 + nt * 16 + rls;
    int t0 = jjh * 32 + mt * 16 + kgs * 4;         // row within 64-tile
    int dt0 = (c2 & 1) * 64 + t0;                  // row within 128-group

    union { ull u; bf16 h[4]; } in;
    in.u = src8[chunk];
    float l2 = l2la[n];
    float s0 = S0g[n];
    float e = exp2f((float)(dt0 + 1) * l2);        // lambda^(dt0+1)
    float lm = exp2f(l2);                          // lambda
#pragma unroll
    for (int r = 0; r < 4; ++r) {
      float s = fmaf(e, s0, (float)in.h[r]);
      int t = t0 + r;
      int byte = (t * (NST * 2) + n * 2) ^ ((t & 15) << 4);
      *(bf16*)(&ss[0] + byte) = (bf16)s;
      e *= lm;
    }
  }
  __syncthreads();

  // ---- K-loop: wave owns o-panel [wid*32, +32); depth-1 rolling C prefetch
  const int o0 = wid * 32;
  f32x4 acc[4][2] = {};
  bf16x8 cf[2];
#pragma unroll
  for (int ot2 = 0; ot2 < 2; ++ot2)
    cf[ot2] = *(const bf16x8*)(Cb + (size_t)(o0 + ot2 * 16 + rl) * NST + kg * 8);
#pragma unroll
  for (int kq = 0; kq < 16; ++kq) {
    const int k0 = kq * 32;
    bf16x8 cfn[2];
    if (kq < 15)
#pragma unroll
      for (int ot2 = 0; ot2 < 2; ++ot2)
        cfn[ot2] = *(const bf16x8*)(Cb + (size_t)(o0 + ot2 * 16 + rl) * NST + k0 + 32 + kg * 8);
    bf16x8 af[4];
#pragma unroll
    for (int mf = 0; mf < 4; ++mf) {
      int t = mf * 16 + rl;
      af[mf] = *(const bf16x8*)(&ss[0] +
          ((t * (NST * 2) + (k0 + kg * 8) * 2) ^ ((t & 15) << 4)));
    }
#pragma unroll
    for (int mf = 0; mf < 4; ++mf)
#pragma unroll
      for (int ot2 = 0; ot2 < 2; ++ot2)
        acc[mf][ot2] = __builtin_amdgcn_mfma_f32_16x16x32_bf16(af[mf], cf[ot2], acc[mf][ot2], 0, 0, 0);
    if (kq < 15) {
      cf[0] = cfn[0]; cf[1] = cfn[1];
    }
  }

  // ---- epilogue: D row=(lane>>4)*4+reg, col=lane&15
#pragma unroll
  for (int mf = 0; mf < 4; ++mf)
#pragma unroll
    for (int ot2 = 0; ot2 < 2; ++ot2)
#pragma unroll
      for (int r = 0; r < 4; ++r) {
        int ml = mf * 16 + kg * 4 + r;
        size_t srow = (size_t)c2 * 64 + ml;
        int o = o0 + ot2 * 16 + rl;
        out[(srow * BATCH + b) * OUTF + o] = acc[mf][ot2][r];
      }
}

// ---------------------------------------------------------------------------
// Fallback: pass0 (Z only) + fused pass1 (R5-proven ~142us)
// ---------------------------------------------------------------------------
__global__ __launch_bounds__(512, 2)
void k_pass0_fb(const float* __restrict__ x, const bf16* __restrict__ Bb,
                const float* __restrict__ lam, float* __restrict__ Z) {
  __shared__ __align__(16) char xs[2][CLEN * INF * 2];

  const int tid = threadIdx.x, wid = tid >> 6, lane = tid & 63;
  const int rl = lane & 15, kg = lane >> 4;
  const int b = blockIdx.x >> 4, cg = blockIdx.x & 15;
  const int n0 = wid * 64;

  float la[4], l4[4], carry[4];
#pragma unroll
  for (int nt = 0; nt < 4; ++nt) {
    float v = lam[n0 + nt * 16 + rl];
    la[nt] = v; l4[nt] = (v * v) * (v * v);
    carry[nt] = 0.0f;
  }

  bf16x8 Breg[8][4];
#pragma unroll
  for (int k = 0; k < 8; ++k)
#pragma unroll
    for (int nt = 0; nt < 4; ++nt)
      Breg[k][nt] = *(const bf16x8*)(Bb + (size_t)(n0 + nt * 16 + rl) * INF + k * 32 + kg * 8);

  {
    float4 xr0[4];
    xload(x + ((size_t)(cg * NJOB * CLEN) * BATCH + b) * INF, tid, xr0);
    xstore(xs[0], tid, xr0);
  }
  __syncthreads();

#pragma unroll
  for (int jj = 0; jj < NJOB; ++jj) {
    const int c = cg * NJOB + jj;
    f32x4 acc[2][4] = {};
#pragma unroll
    for (int k = 0; k < 8; ++k) {
      bf16x8 af[2];
#pragma unroll
      for (int mt = 0; mt < 2; ++mt) {
        int row = mt * 16 + rl;
        int byte = (row * (INF * 2) + (k * 32 + kg * 8) * 2) ^ (rl << 4);
        af[mt] = *(const bf16x8*)(&xs[jj & 1][0] + byte);
      }
#pragma unroll
      for (int mt = 0; mt < 2; ++mt)
#pragma unroll
        for (int nt = 0; nt < 4; ++nt)
          acc[mt][nt] = __builtin_amdgcn_mfma_f32_16x16x32_bf16(af[mt], Breg[k][nt], acc[mt][nt], 0, 0, 0);
    }

    if (jj < NJOB - 1) {
      float4 xr[4];
      xload(x + ((size_t)((c + 1) * CLEN) * BATCH + b) * INF, tid, xr);
      reg_scan(acc, carry, la, l4, kg, rl);
      xstore(xs[(jj + 1) & 1], tid, xr);
      __syncthreads();
    } else {
      reg_scan(acc, carry, la, l4, kg, rl);
      if (kg == 0)
#pragma unroll
        for (int nt = 0; nt < 4; ++nt)
          Z[((size_t)cg * BATCH + b) * NST + n0 + nt * 16 + rl] = carry[nt];
    }
  }
}

__global__ __launch_bounds__(512)
void k_pass1_fb(const float* __restrict__ x, const bf16* __restrict__ Bb,
                const bf16* __restrict__ Cb, const float* __restrict__ lam,
                const float* __restrict__ S0, float* __restrict__ out,
                float* __restrict__ fin) {
  __shared__ __align__(16) char xs[2][CLEN * INF * 2];
  __shared__ __align__(16) char ss[CLEN * NST * 2];

  const int tid = threadIdx.x, wid = tid >> 6, lane = tid & 63;
  const int rl = lane & 15, kg = lane >> 4;
  const int b = blockIdx.x >> 4, cg = blockIdx.x & 15;
  const int n0 = wid * 64;

  float la[4], l4[4], carry[4];
#pragma unroll
  for (int nt = 0; nt < 4; ++nt) {
    float v = lam[n0 + nt * 16 + rl];
    la[nt] = v; l4[nt] = (v * v) * (v * v);
    carry[nt] = S0[((size_t)cg * BATCH + b) * NST + n0 + nt * 16 + rl];
  }
  {
    float4 xr0[4];
    xload(x + ((size_t)(cg * NJOB * CLEN) * BATCH + b) * INF, tid, xr0);
    xstore(xs[0], tid, xr0);
  }
  __syncthreads();

#pragma unroll
  for (int jj = 0; jj < NJOB; ++jj) {
    const int c = cg * NJOB + jj;
    f32x4 acc[2][4] = {};
    gemm1_l2(&xs[jj & 1][0], Bb, acc, n0, rl, kg);
    {
      float4 xr[4];
      const int lastj = (jj == NJOB - 1);
      if (!lastj)
        xload(x + ((size_t)((c + 1) * CLEN) * BATCH + b) * INF, tid, xr);
      reg_scan(acc, carry, la, l4, kg, rl);
      if (c == NCH - 1 && kg == 0)
#pragma unroll
        for (int nt = 0; nt < 4; ++nt)
          fin[(size_t)b * NST + n0 + nt * 16 + rl] = carry[nt];
      __syncthreads();
#pragma unroll
      for (int mt = 0; mt < 2; ++mt)
#pragma unroll
        for (int nt = 0; nt < 4; ++nt)
#pragma unroll
          for (int r = 0; r < 4; ++r) {
            int t = mt * 16 + kg * 4 + r;
            int n = n0 + nt * 16 + rl;
            int byte = (t * (NST * 2) + n * 2) ^ ((t & 15) << 4);
            *(bf16*)(&ss[0] + byte) = (bf16)acc[mt][nt][r];
          }
      if (!lastj) xstore(xs[(jj + 1) & 1], tid, xr);
    }
    __syncthreads();

    const int o0 = wid * 32;
    f32x4 a2[2][2] = {};
#pragma unroll
    for (int k0 = 0; k0 < NST; k0 += 32) {
      bf16x8 af[2], cf[2];
#pragma unroll
      for (int mt = 0; mt < 2; ++mt) {
        int t = mt * 16 + rl;
        int byte = (t * (NST * 2) + (k0 + kg * 8) * 2) ^ (rl << 4);
        af[mt] = *(const bf16x8*)(&ss[0] + byte);
      }
#pragma unroll
      for (int ot = 0; ot < 2; ++ot)
        cf[ot] = *(const bf16x8*)(Cb + (size_t)(o0 + ot * 16 + rl) * NST + k0 + kg * 8);
#pragma unroll
      for (int mt = 0; mt < 2; ++mt)
#pragma unroll
        for (int ot = 0; ot < 2; ++ot)
          a2[mt][ot] = __builtin_amdgcn_mfma_f32_16x16x32_bf16(af[mt], cf[ot], a2[mt][ot], 0, 0, 0);
    }
#pragma unroll
    for (int mt = 0; mt < 2; ++mt)
#pragma unroll
      for (int ot = 0; ot < 2; ++ot)
#pragma unroll
        for (int r = 0; r < 4; ++r) {
          int t = mt * 16 + kg * 4 + r;
          int o = o0 + ot * 16 + rl;
          out[(((size_t)(c * CLEN + t)) * BATCH + b) * OUTF + o] = a2[mt][ot][r];
        }
  }
}

// ---------------------------------------------------------------------------
extern "C" void kernel_launch(void* const* d_in, const int* in_sizes, int n_in,
                              void* d_out, int out_size, void* d_ws, size_t ws_size,
                              hipStream_t stream) {
  const float* x  = (const float*)d_in[0];
  const float* ll = (const float*)d_in[1];
  const float* Bm = (const float*)d_in[2];
  const float* Cm = (const float*)d_in[3];

  char* ws = (char*)d_ws;
  float* lam  = (float*)(ws);
  float* lamG = (float*)(ws + 2048);
  float* l2la = (float*)(ws + 4096);
  bf16*  Bb   = (bf16*)(ws + 6144);
  bf16*  Cb   = (bf16*)((char*)Bb + (size_t)NST * INF * 2);
  float* Z    = (float*)((char*)Cb + (size_t)OUTF * NST * 2);
  float* S0   = (float*)((char*)Z + (size_t)NCG * BATCH * NST * 4);
  ull*   bfrag= (ull*)((char*)S0 + (size_t)NCG * BATCH * NST * 4);
  const size_t NEED = ((char*)bfrag - ws) + (size_t)SEQ * BATCH * NST * 2;  // ~67MB

  float* out = (float*)d_out;
  float* fin = out + (size_t)SEQ * BATCH * OUTF;

  k_prep<<<dim3(512), dim3(256), 0, stream>>>(ll, Bm, Cm, lam, lamG, l2la, Bb, Cb);
  if (ws_size >= NEED) {
    k_pass0f<<<dim3(NBLK), dim3(512), 0, stream>>>(x, Bb, lam, Z, bfrag);
    k_chain<<<dim3(BATCH, 4), dim3(128), 0, stream>>>(Z, lamG, S0, fin);
    k_gemm2g<<<dim3(1024), dim3(512), 0, stream>>>(bfrag, Cb, S0, l2la, out);
  } else {
    k_pass0_fb<<<dim3(NBLK), dim3(512), 0, stream>>>(x, Bb, lam, Z);
    k_chain<<<dim3(BATCH, 4), dim3(128), 0, stream>>>(Z, lamG, S0, fin);
    k_pass1_fb<<<dim3(NBLK), dim3(512), 0, stream>>>(x, Bb, Cb, lam, S0, out, fin);
  }
}